// Round 1
// baseline (574.225 us; speedup 1.0000x reference)
//
#include <hip/hip_runtime.h>

// ---------------------------------------------------------------------------
// Kernel 1: per-sample encoder conv stack + dense layers + both MLPs.
// One block (256 threads) per sample. Everything staged through LDS.
// Writes p_r (20) and v (40) per sample into workspace, and the dp/dv
// portions of the output directly.
// ---------------------------------------------------------------------------
__global__ __launch_bounds__(256) void enc_mlp_kernel(
    const float* __restrict__ xtraj, const float* __restrict__ x,
    const float* __restrict__ x_img,
    const float* __restrict__ cw1, const float* __restrict__ cb1,
    const float* __restrict__ cw2, const float* __restrict__ cb2,
    const float* __restrict__ w3, const float* __restrict__ b3,
    const float* __restrict__ w4, const float* __restrict__ b4,
    const float* __restrict__ pw1, const float* __restrict__ pb1,
    const float* __restrict__ pw2, const float* __restrict__ pb2,
    const float* __restrict__ pw3, const float* __restrict__ pb3,
    const float* __restrict__ vw1, const float* __restrict__ vb1,
    const float* __restrict__ vw2, const float* __restrict__ vb2,
    const float* __restrict__ vw3, const float* __restrict__ vb3,
    float* __restrict__ out, float* __restrict__ ws_pr, float* __restrict__ ws_v)
{
    const int b = blockIdx.x;
    const int tid = threadIdx.x;

    __shared__ float s_img[2500];   // 50x50 image
    __shared__ float s_h1[4000];    // conv1 pooled relu: [10][20][20]
    __shared__ float s_tmp[5120];   // scratch: conv pre-pool / MLP hiddens
    __shared__ float s_h2[320];     // conv2 pooled relu flattened
    __shared__ float s_hc[145];     // concat(e, xtraj)
    __shared__ float s_t1[150];     // dense hidden

    // ---- load image ----
    const float* img = x_img + (size_t)b * 2500;
    for (int i = tid; i < 2500; i += 256) s_img[i] = img[i];
    __syncthreads();

    // ---- conv1 (11x11, VALID: 50->40) + maxpool2 + relu -> s_h1 ----
    for (int oc = 0; oc < 10; ++oc) {
        const float* w = cw1 + oc * 121;  // wave-uniform -> scalar loads
        for (int it = 0; it < 7; ++it) {
            int pos = it * 256 + tid;
            if (pos < 1600) {
                int y = pos / 40, xx = pos % 40;
                float acc = 0.f;
                #pragma unroll
                for (int ky = 0; ky < 11; ++ky) {
                    #pragma unroll
                    for (int kx = 0; kx < 11; ++kx)
                        acc += s_img[(y + ky) * 50 + xx + kx] * w[ky * 11 + kx];
                }
                s_tmp[pos] = acc;
            }
        }
        __syncthreads();
        for (int it = 0; it < 2; ++it) {
            int pos = it * 256 + tid;
            if (pos < 400) {
                int py = pos / 20, px = pos % 20;
                int base = (2 * py) * 40 + 2 * px;
                float m = fmaxf(fmaxf(s_tmp[base], s_tmp[base + 1]),
                                fmaxf(s_tmp[base + 40], s_tmp[base + 41]));
                s_h1[oc * 400 + pos] = fmaxf(m + cb1[oc], 0.f);
            }
        }
        __syncthreads();
    }

    // ---- conv2 (5x5, VALID: 20->16), 10 in-ch, 20 out-ch -> s_tmp[20*256] ----
    {
        int y = tid / 16, xx = tid % 16;   // exactly 256 positions per oc
        for (int oc = 0; oc < 20; ++oc) {
            const float* w = cw2 + oc * 250;  // uniform -> scalar loads
            float acc = 0.f;
            #pragma unroll
            for (int ic = 0; ic < 10; ++ic) {
                #pragma unroll
                for (int ky = 0; ky < 5; ++ky) {
                    #pragma unroll
                    for (int kx = 0; kx < 5; ++kx)
                        acc += s_h1[ic * 400 + (y + ky) * 20 + xx + kx] * w[ic * 25 + ky * 5 + kx];
                }
            }
            s_tmp[oc * 256 + tid] = acc;
        }
    }
    __syncthreads();

    // ---- maxpool4 + bias + relu -> s_h2[320] (flatten order oc*16+py*4+px) ----
    for (int it = 0; it < 2; ++it) {
        int item = it * 256 + tid;
        if (item < 320) {
            int oc = item / 16, py = (item / 4) % 4, px = item % 4;
            float m = -1e30f;
            #pragma unroll
            for (int i = 0; i < 4; ++i) {
                #pragma unroll
                for (int j = 0; j < 4; ++j)
                    m = fmaxf(m, s_tmp[oc * 256 + (4 * py + i) * 16 + 4 * px + j]);
            }
            s_h2[item] = fmaxf(m + cb2[oc], 0.f);
        }
    }
    __syncthreads();

    // ---- dense 320 -> 150, relu ----
    if (tid < 150) {
        const float* w = w3 + tid * 320;
        float acc = b3[tid];
        for (int k = 0; k < 320; ++k) acc += s_h2[k] * w[k];
        s_t1[tid] = fmaxf(acc, 0.f);
    }
    __syncthreads();

    // ---- dense 150 -> 100, relu -> s_hc[0:100]; concat xtraj -> s_hc[100:145] ----
    if (tid < 100) {
        const float* w = w4 + tid * 150;
        float acc = b4[tid];
        for (int k = 0; k < 150; ++k) acc += s_t1[k] * w[k];
        s_hc[tid] = fmaxf(acc, 0.f);
    }
    if (tid >= 100 && tid < 145) s_hc[tid] = xtraj[b * 45 + (tid - 100)];
    __syncthreads();

    // ---- two MLPs in parallel: p-net on threads 0..99, v-net on 128..227 ----
    float* ph1 = s_tmp;        // 100
    float* ph2 = s_tmp + 128;  // 100
    float* vh1 = s_tmp + 256;  // 100
    float* vh2 = s_tmp + 384;  // 100

    if (tid < 100) {
        const float* w = pw1 + tid * 145;
        float acc = pb1[tid];
        for (int k = 0; k < 145; ++k) acc += s_hc[k] * w[k];
        ph1[tid] = fmaxf(acc, 0.f);
    } else if (tid >= 128 && tid < 228) {
        int i = tid - 128;
        const float* w = vw1 + i * 145;
        float acc = vb1[i];
        for (int k = 0; k < 145; ++k) acc += s_hc[k] * w[k];
        vh1[i] = fmaxf(acc, 0.f);
    }
    __syncthreads();

    if (tid < 100) {
        const float* w = pw2 + tid * 100;
        float acc = pb2[tid];
        for (int k = 0; k < 100; ++k) acc += ph1[k] * w[k];
        ph2[tid] = fmaxf(acc, 0.f);
    } else if (tid >= 128 && tid < 228) {
        int i = tid - 128;
        const float* w = vw2 + i * 100;
        float acc = vb2[i];
        for (int k = 0; k < 100; ++k) acc += vh1[k] * w[k];
        vh2[i] = fmaxf(acc, 0.f);
    }
    __syncthreads();

    if (tid < 20) {
        const float* w = pw3 + tid * 100;
        float acc = pb3[tid];
        for (int k = 0; k < 100; ++k) acc += ph2[k] * w[k];
        ws_pr[b * 20 + tid] = acc;
        // out[40:60] = 100 * 10 * (p_r - x[:, 0:20])
        out[b * 100 + 40 + tid] = 1000.f * (acc - x[b * 160 + tid]);
    } else if (tid >= 128 && tid < 168) {
        int i = tid - 128;
        const float* w = vw3 + i * 100;
        float acc = vb3[i];
        for (int k = 0; k < 100; ++k) acc += vh2[k] * w[k];
        ws_v[b * 40 + i] = acc;
        // out[60:100] = 100 * 10 * (v - x[:, 120:160])
        out[b * 100 + 60 + i] = 1000.f * (acc - x[b * 160 + 120 + i]);
    }
}

// ---------------------------------------------------------------------------
// Kernel 2: per-(sample,t) LP via PDHG, one thread per problem.
// A (17x24) is sparse with ~56 nnz described by ~26 scalar coefficients;
// the whole iteration is hand-unrolled scalar code, state in registers.
// ---------------------------------------------------------------------------
struct Coef {
    float c24, c25, c26, c27, c28, c29, c210, c211;
    float v0, v1, v2, v3, v4, v5;
    float fc0, fc1, fc2, fc3, fc4, fc5;
    float fe0, fe1, fe2, fe3, fe4, fe5, fe6, fe7;
};

__device__ __forceinline__ void Az(const Coef& c, const float* z, float* w) {
    w[0] = z[4] + z[5] + z[6] + z[7] + z[8] + z[9];
    w[1] = z[10] + z[11];
    w[2] = c.c24 * z[4] + c.c25 * z[5] + c.c26 * z[6] + c.c27 * z[7]
         + c.c28 * z[8] + c.c29 * z[9] + c.c210 * z[10] + c.c211 * z[11];
    w[3] = z[0] - c.v0 * z[12] - c.v2 * z[14];
    w[4] = z[2] - c.v1 * z[12] - c.v3 * z[14];
    w[5] = z[12] + z[14];
    w[6] = z[1] - c.v2 * z[13] - c.v4 * z[15];
    w[7] = z[3] - c.v3 * z[13] - c.v5 * z[15];
    w[8] = z[13] + z[15];
    w[9]  = c.fc0 * z[16] + c.fc2 * z[18] - z[4];
    w[10] = c.fc1 * z[16] + c.fc3 * z[18] - z[6];
    w[11] = c.fc2 * z[17] + c.fc4 * z[19] - z[5];
    w[12] = c.fc3 * z[17] + c.fc5 * z[19] - z[7];
    w[13] = c.fe0 * z[20] + c.fe2 * z[21] - z[8];
    w[14] = c.fe1 * z[20] + c.fe3 * z[21] - z[10];
    w[15] = c.fe4 * z[22] + c.fe6 * z[23] - z[9];
    w[16] = c.fe5 * z[22] + c.fe7 * z[23] - z[11];
}

__device__ __forceinline__ void ATy(const Coef& c, const float* y, float* g) {
    g[0] = y[3]; g[1] = y[6]; g[2] = y[4]; g[3] = y[7];
    g[4] = y[0] + c.c24 * y[2] - y[9];
    g[5] = y[0] + c.c25 * y[2] - y[11];
    g[6] = y[0] + c.c26 * y[2] - y[10];
    g[7] = y[0] + c.c27 * y[2] - y[12];
    g[8] = y[0] + c.c28 * y[2] - y[13];
    g[9] = y[0] + c.c29 * y[2] - y[15];
    g[10] = y[1] + c.c210 * y[2] - y[14];
    g[11] = y[1] + c.c211 * y[2] - y[16];
    g[12] = -c.v0 * y[3] - c.v1 * y[4] + y[5];
    g[13] = -c.v2 * y[6] - c.v3 * y[7] + y[8];
    g[14] = -c.v2 * y[3] - c.v3 * y[4] + y[5];
    g[15] = -c.v4 * y[6] - c.v5 * y[7] + y[8];
    g[16] = c.fc0 * y[9]  + c.fc1 * y[10];
    g[17] = c.fc2 * y[11] + c.fc3 * y[12];
    g[18] = c.fc2 * y[9]  + c.fc3 * y[10];
    g[19] = c.fc4 * y[11] + c.fc5 * y[12];
    g[20] = c.fe0 * y[13] + c.fe1 * y[14];
    g[21] = c.fe2 * y[13] + c.fe3 * y[14];
    g[22] = c.fe4 * y[15] + c.fe5 * y[16];
    g[23] = c.fe6 * y[15] + c.fe7 * y[16];
}

__global__ __launch_bounds__(64) void lp_kernel(
    const float* __restrict__ xtraj, const float* __restrict__ x,
    const float* __restrict__ ws_pr, const float* __restrict__ ws_v,
    float* __restrict__ out, int nprob)
{
    int p = blockIdx.x * 64 + threadIdx.x;
    if (p >= nprob) return;
    int b = p / 5, t = p % 5;
    const float* xt = xtraj + b * 45;
    const float* xb = x + b * 160;

    float r0 = xt[t], r1 = xt[5 + t];
    float ddr0 = xt[30 + t], ddr1 = xt[35 + t], ddr2 = xt[40 + t];

    float fc[8], fce[8], pe[4], vv[8], pr[4];
    #pragma unroll
    for (int i = 0; i < 8; ++i) fc[i] = xb[20 + 5 * i + t];
    #pragma unroll
    for (int i = 0; i < 4; ++i) pe[i] = xb[60 + 5 * i + t];
    #pragma unroll
    for (int i = 0; i < 8; ++i) fce[i] = xb[80 + 5 * i + t];
    #pragma unroll
    for (int i = 0; i < 8; ++i) vv[i] = ws_v[b * 40 + 5 * i + t];
    #pragma unroll
    for (int i = 0; i < 4; ++i) pr[i] = ws_pr[b * 20 + 5 * i + t];

    Coef co;
    co.c26 = pr[0] - r0;  co.c24 = r1 - pr[2];
    co.c27 = pr[1] - r0;  co.c25 = r1 - pr[3];
    co.c210 = pe[0] - r0; co.c28 = r1 - pe[2];
    co.c211 = pe[1] - r0; co.c29 = r1 - pe[3];
    co.v0 = vv[0]; co.v1 = vv[1]; co.v2 = vv[2];
    co.v3 = vv[3]; co.v4 = vv[4]; co.v5 = vv[5];
    co.fc0 = fc[0]; co.fc1 = fc[1]; co.fc2 = fc[2];
    co.fc3 = fc[3]; co.fc4 = fc[4]; co.fc5 = fc[5];
    co.fe0 = fce[0]; co.fe1 = fce[1]; co.fe2 = fce[2]; co.fe3 = fce[3];
    co.fe4 = fce[4]; co.fe5 = fce[5]; co.fe6 = fce[6]; co.fe7 = fce[7];

    // ---- spectral norm: 25 power iterations on A^T A ----
    float u[24], w[17], g[24];
    #pragma unroll
    for (int j = 0; j < 24; ++j) u[j] = 1.f;
    for (int it = 0; it < 25; ++it) {
        Az(co, u, w);
        ATy(co, w, u);
        float s = 0.f;
        #pragma unroll
        for (int j = 0; j < 24; ++j) s += u[j] * u[j];
        float inv = 1.f / (sqrtf(s) + 1e-12f);
        #pragma unroll
        for (int j = 0; j < 24; ++j) u[j] *= inv;
    }
    Az(co, u, w);
    float s2 = 0.f;
    #pragma unroll
    for (int e = 0; e < 17; ++e) s2 += w[e] * w[e];
    float L = sqrtf(s2);
    float tau = 0.9f / (L + 1e-8f);   // sig == tau

    // ---- PDHG ----
    float z[24], zb[24], y[17];
    #pragma unroll
    for (int j = 0; j < 24; ++j) { z[j] = 0.f; zb[j] = 0.f; }
    #pragma unroll
    for (int e = 0; e < 17; ++e) y[e] = 0.f;

    for (int it = 0; it < 400; ++it) {
        Az(co, zb, w);
        y[0] += tau * (w[0] - ddr0);
        y[1] += tau * (w[1] - ddr1);
        y[2] += tau * (w[2] - ddr2);
        y[3] += tau * w[3];
        y[4] += tau * w[4];
        y[5] += tau * (w[5] - 1.f);
        y[6] += tau * w[6];
        y[7] += tau * w[7];
        y[8] += tau * (w[8] - 1.f);
        #pragma unroll
        for (int e = 9; e < 17; ++e) y[e] += tau * w[e];

        ATy(co, y, g);
        #pragma unroll
        for (int j = 0; j < 24; ++j) {
            float gg = z[j] - tau * g[j];
            float zn;
            if (j >= 4 && j < 8) {                // L1 prox (soft threshold)
                float a = fmaxf(fabsf(gg) - tau, 0.f);
                zn = copysignf(a, gg);
            } else if (j >= 12) {                 // nonneg projection
                zn = fmaxf(gg, 0.f);
            } else {
                zn = gg;
            }
            zb[j] = 2.f * zn - z[j];
            z[j] = zn;
        }
    }

    // ---- write p, f portions of output ----
    float* ob = out + b * 100;
    #pragma unroll
    for (int i = 0; i < 4; ++i) {
        ob[i * 5 + t]      = 100.f * z[i];
        ob[20 + i * 5 + t] = 100.f * z[4 + i];
    }
}

extern "C" void kernel_launch(void* const* d_in, const int* in_sizes, int n_in,
                              void* d_out, int out_size, void* d_ws, size_t ws_size,
                              hipStream_t stream) {
    const float* xtraj = (const float*)d_in[0];
    const float* x     = (const float*)d_in[1];
    const float* x_img = (const float*)d_in[2];
    const float* cw1 = (const float*)d_in[3];
    const float* cb1 = (const float*)d_in[4];
    const float* cw2 = (const float*)d_in[5];
    const float* cb2 = (const float*)d_in[6];
    const float* w3  = (const float*)d_in[7];
    const float* b3  = (const float*)d_in[8];
    const float* w4  = (const float*)d_in[9];
    const float* b4  = (const float*)d_in[10];
    const float* pw1 = (const float*)d_in[11];
    const float* pb1 = (const float*)d_in[12];
    const float* pw2 = (const float*)d_in[13];
    const float* pb2 = (const float*)d_in[14];
    const float* pw3 = (const float*)d_in[15];
    const float* pb3 = (const float*)d_in[16];
    const float* vw1 = (const float*)d_in[17];
    const float* vb1 = (const float*)d_in[18];
    const float* vw2 = (const float*)d_in[19];
    const float* vb2 = (const float*)d_in[20];
    const float* vw3 = (const float*)d_in[21];
    const float* vb3 = (const float*)d_in[22];

    float* out = (float*)d_out;
    const int Bn = in_sizes[0] / 45;

    float* ws_pr = (float*)d_ws;          // Bn*20 floats
    float* ws_v  = ws_pr + (size_t)Bn * 20;  // Bn*40 floats

    enc_mlp_kernel<<<Bn, 256, 0, stream>>>(
        xtraj, x, x_img, cw1, cb1, cw2, cb2, w3, b3, w4, b4,
        pw1, pb1, pw2, pb2, pw3, pb3, vw1, vb1, vw2, vb2, vw3, vb3,
        out, ws_pr, ws_v);

    const int nprob = Bn * 5;
    lp_kernel<<<(nprob + 63) / 64, 64, 0, stream>>>(xtraj, x, ws_pr, ws_v, out, nprob);
}

// Round 2
// 332.444 us; speedup vs baseline: 1.7273x; 1.7273x over previous
//
#include <hip/hip_runtime.h>

// ---------------------------------------------------------------------------
// Kernel 1: per-sample encoder conv stack + dense layers + both MLPs.
// One block (256 threads) per sample.
// conv1: register-tiled 2x2 quads, all 10 ocs per thread, pool fused.
// conv2: register-tiled 4x4 block = one pooled output per thread, weights
//        staged in LDS (broadcast reads), pool fused.
// ---------------------------------------------------------------------------
__global__ __launch_bounds__(256) void enc_mlp_kernel(
    const float* __restrict__ xtraj, const float* __restrict__ x,
    const float* __restrict__ x_img,
    const float* __restrict__ cw1, const float* __restrict__ cb1,
    const float* __restrict__ cw2, const float* __restrict__ cb2,
    const float* __restrict__ w3, const float* __restrict__ b3,
    const float* __restrict__ w4, const float* __restrict__ b4,
    const float* __restrict__ pw1, const float* __restrict__ pb1,
    const float* __restrict__ pw2, const float* __restrict__ pb2,
    const float* __restrict__ pw3, const float* __restrict__ pb3,
    const float* __restrict__ vw1, const float* __restrict__ vb1,
    const float* __restrict__ vw2, const float* __restrict__ vb2,
    const float* __restrict__ vw3, const float* __restrict__ vb3,
    float* __restrict__ out, float* __restrict__ ws_pr, float* __restrict__ ws_v)
{
    const int b = blockIdx.x;
    const int tid = threadIdx.x;

    __shared__ __align__(16) float s_img[2500];   // 50x50 image
    __shared__ __align__(16) float s_w2[5000];    // conv2 weights [oc][ic][5][5]
    __shared__ __align__(16) float s_h1[4000];    // conv1 pooled relu: [10][20][20]
    __shared__ __align__(16) float s_h2[320];     // conv2 pooled relu flattened
    __shared__ float s_hc[145];                   // concat(e, xtraj)
    __shared__ float s_t1[152];                   // dense hidden (150)
    __shared__ float s_m1[256];                   // ph1[0:100], vh1[128:228]
    __shared__ float s_m2[256];                   // ph2[0:100], vh2[128:228]

    // ---- stage image + conv2 weights ----
    const float* img = x_img + (size_t)b * 2500;
    for (int i = tid; i < 2500; i += 256) s_img[i] = img[i];
    for (int i = tid; i < 5000; i += 256) s_w2[i] = cw2[i];
    __syncthreads();

    // ---- conv1 (11x11, 50->40) + maxpool2 + relu, register-tiled ----
    // Each thread: one 2x2 pre-pool quad, ALL 10 output channels.
    for (int qq = tid; qq < 400; qq += 256) {
        const int py = qq / 20, px = qq % 20;
        const int C = 2 * px;
        float acc0[10], acc1[10], acc2[10], acc3[10];
        #pragma unroll
        for (int oc = 0; oc < 10; ++oc) { acc0[oc] = 0.f; acc1[oc] = 0.f; acc2[oc] = 0.f; acc3[oc] = 0.f; }
        for (int r = 0; r < 12; ++r) {           // image rows 2py+r
            float v[12];
            #pragma unroll
            for (int j = 0; j < 6; ++j) {
                float2 t = *(const float2*)&s_img[(2 * py + r) * 50 + C + 2 * j];
                v[2 * j] = t.x; v[2 * j + 1] = t.y;
            }
            if (r < 11) {                        // contributes to out-row 2py (k=r)
                #pragma unroll
                for (int oc = 0; oc < 10; ++oc) {
                    #pragma unroll
                    for (int kx = 0; kx < 11; ++kx) {
                        float w0 = cw1[oc * 121 + r * 11 + kx];
                        acc0[oc] = fmaf(v[kx], w0, acc0[oc]);
                        acc1[oc] = fmaf(v[kx + 1], w0, acc1[oc]);
                    }
                }
            }
            if (r >= 1) {                        // contributes to out-row 2py+1 (k=r-1)
                #pragma unroll
                for (int oc = 0; oc < 10; ++oc) {
                    #pragma unroll
                    for (int kx = 0; kx < 11; ++kx) {
                        float w1 = cw1[oc * 121 + (r - 1) * 11 + kx];
                        acc2[oc] = fmaf(v[kx], w1, acc2[oc]);
                        acc3[oc] = fmaf(v[kx + 1], w1, acc3[oc]);
                    }
                }
            }
        }
        #pragma unroll
        for (int oc = 0; oc < 10; ++oc) {
            float m = fmaxf(fmaxf(acc0[oc], acc1[oc]), fmaxf(acc2[oc], acc3[oc]));
            s_h1[oc * 400 + qq] = fmaxf(m + cb1[oc], 0.f);
        }
    }
    __syncthreads();

    // ---- conv2 (5x5, 20->16, 10ic->20oc) + maxpool4 + relu, register-tiled ----
    // Each thread: one pooled output = 4x4 pre-pool block for one oc.
    for (int u = tid; u < 320; u += 256) {
        const int oc = u >> 4, cell = u & 15;
        const int R0 = (cell >> 2) * 4, C0 = (cell & 3) * 4;
        float acc[16];
        #pragma unroll
        for (int i = 0; i < 16; ++i) acc[i] = 0.f;
        for (int ic = 0; ic < 10; ++ic) {
            const float* hb = &s_h1[ic * 400];
            const float* wb = &s_w2[oc * 250 + ic * 25];
            float v[8][8];
            #pragma unroll
            for (int r = 0; r < 8; ++r) {
                float4 t0 = *(const float4*)&hb[(R0 + r) * 20 + C0];
                float4 t1 = *(const float4*)&hb[(R0 + r) * 20 + C0 + 4];
                v[r][0] = t0.x; v[r][1] = t0.y; v[r][2] = t0.z; v[r][3] = t0.w;
                v[r][4] = t1.x; v[r][5] = t1.y; v[r][6] = t1.z; v[r][7] = t1.w;
            }
            #pragma unroll
            for (int k = 0; k < 5; ++k) {
                #pragma unroll
                for (int kx = 0; kx < 5; ++kx) {
                    float wv = wb[k * 5 + kx];
                    #pragma unroll
                    for (int o = 0; o < 4; ++o) {
                        #pragma unroll
                        for (int c = 0; c < 4; ++c)
                            acc[o * 4 + c] = fmaf(v[o + k][c + kx], wv, acc[o * 4 + c]);
                    }
                }
            }
        }
        float m = acc[0];
        #pragma unroll
        for (int i = 1; i < 16; ++i) m = fmaxf(m, acc[i]);
        s_h2[u] = fmaxf(m + cb2[oc], 0.f);   // flatten order oc*16 + py*4 + px
    }
    __syncthreads();

    // ---- dense 320 -> 150, relu ----
    if (tid < 150) {
        const float* w = w3 + tid * 320;
        float acc = b3[tid];
        for (int k = 0; k < 320; ++k) acc = fmaf(s_h2[k], w[k], acc);
        s_t1[tid] = fmaxf(acc, 0.f);
    }
    __syncthreads();

    // ---- dense 150 -> 100, relu -> s_hc[0:100]; concat xtraj -> s_hc[100:145] ----
    if (tid < 100) {
        const float* w = w4 + tid * 150;
        float acc = b4[tid];
        for (int k = 0; k < 150; ++k) acc = fmaf(s_t1[k], w[k], acc);
        s_hc[tid] = fmaxf(acc, 0.f);
    }
    if (tid >= 100 && tid < 145) s_hc[tid] = xtraj[b * 45 + (tid - 100)];
    __syncthreads();

    // ---- two MLPs in parallel: p-net on threads 0..99, v-net on 128..227 ----
    if (tid < 100) {
        const float* w = pw1 + tid * 145;
        float acc = pb1[tid];
        for (int k = 0; k < 145; ++k) acc = fmaf(s_hc[k], w[k], acc);
        s_m1[tid] = fmaxf(acc, 0.f);
    } else if (tid >= 128 && tid < 228) {
        int i = tid - 128;
        const float* w = vw1 + i * 145;
        float acc = vb1[i];
        for (int k = 0; k < 145; ++k) acc = fmaf(s_hc[k], w[k], acc);
        s_m1[tid] = fmaxf(acc, 0.f);
    }
    __syncthreads();

    if (tid < 100) {
        const float* w = pw2 + tid * 100;
        float acc = pb2[tid];
        for (int k = 0; k < 100; ++k) acc = fmaf(s_m1[k], w[k], acc);
        s_m2[tid] = fmaxf(acc, 0.f);
    } else if (tid >= 128 && tid < 228) {
        int i = tid - 128;
        const float* w = vw2 + i * 100;
        float acc = vb2[i];
        for (int k = 0; k < 100; ++k) acc = fmaf(s_m1[128 + k], w[k], acc);
        s_m2[tid] = fmaxf(acc, 0.f);
    }
    __syncthreads();

    if (tid < 20) {
        const float* w = pw3 + tid * 100;
        float acc = pb3[tid];
        for (int k = 0; k < 100; ++k) acc = fmaf(s_m2[k], w[k], acc);
        ws_pr[b * 20 + tid] = acc;
        out[b * 100 + 40 + tid] = 1000.f * (acc - x[b * 160 + tid]);
    } else if (tid >= 128 && tid < 168) {
        int i = tid - 128;
        const float* w = vw3 + i * 100;
        float acc = vb3[i];
        for (int k = 0; k < 100; ++k) acc = fmaf(s_m2[128 + k], w[k], acc);
        ws_v[b * 40 + i] = acc;
        out[b * 100 + 60 + i] = 1000.f * (acc - x[b * 160 + 120 + i]);
    }
}

// ---------------------------------------------------------------------------
// Kernel 2: per-(sample,t) LP via PDHG, one thread per problem.
// ---------------------------------------------------------------------------
struct Coef {
    float c24, c25, c26, c27, c28, c29, c210, c211;
    float v0, v1, v2, v3, v4, v5;
    float fc0, fc1, fc2, fc3, fc4, fc5;
    float fe0, fe1, fe2, fe3, fe4, fe5, fe6, fe7;
};

__device__ __forceinline__ void Az(const Coef& c, const float* z, float* w) {
    w[0] = z[4] + z[5] + z[6] + z[7] + z[8] + z[9];
    w[1] = z[10] + z[11];
    w[2] = c.c24 * z[4] + c.c25 * z[5] + c.c26 * z[6] + c.c27 * z[7]
         + c.c28 * z[8] + c.c29 * z[9] + c.c210 * z[10] + c.c211 * z[11];
    w[3] = z[0] - c.v0 * z[12] - c.v2 * z[14];
    w[4] = z[2] - c.v1 * z[12] - c.v3 * z[14];
    w[5] = z[12] + z[14];
    w[6] = z[1] - c.v2 * z[13] - c.v4 * z[15];
    w[7] = z[3] - c.v3 * z[13] - c.v5 * z[15];
    w[8] = z[13] + z[15];
    w[9]  = c.fc0 * z[16] + c.fc2 * z[18] - z[4];
    w[10] = c.fc1 * z[16] + c.fc3 * z[18] - z[6];
    w[11] = c.fc2 * z[17] + c.fc4 * z[19] - z[5];
    w[12] = c.fc3 * z[17] + c.fc5 * z[19] - z[7];
    w[13] = c.fe0 * z[20] + c.fe2 * z[21] - z[8];
    w[14] = c.fe1 * z[20] + c.fe3 * z[21] - z[10];
    w[15] = c.fe4 * z[22] + c.fe6 * z[23] - z[9];
    w[16] = c.fe5 * z[22] + c.fe7 * z[23] - z[11];
}

__device__ __forceinline__ void ATy(const Coef& c, const float* y, float* g) {
    g[0] = y[3]; g[1] = y[6]; g[2] = y[4]; g[3] = y[7];
    g[4] = y[0] + c.c24 * y[2] - y[9];
    g[5] = y[0] + c.c25 * y[2] - y[11];
    g[6] = y[0] + c.c26 * y[2] - y[10];
    g[7] = y[0] + c.c27 * y[2] - y[12];
    g[8] = y[0] + c.c28 * y[2] - y[13];
    g[9] = y[0] + c.c29 * y[2] - y[15];
    g[10] = y[1] + c.c210 * y[2] - y[14];
    g[11] = y[1] + c.c211 * y[2] - y[16];
    g[12] = -c.v0 * y[3] - c.v1 * y[4] + y[5];
    g[13] = -c.v2 * y[6] - c.v3 * y[7] + y[8];
    g[14] = -c.v2 * y[3] - c.v3 * y[4] + y[5];
    g[15] = -c.v4 * y[6] - c.v5 * y[7] + y[8];
    g[16] = c.fc0 * y[9]  + c.fc1 * y[10];
    g[17] = c.fc2 * y[11] + c.fc3 * y[12];
    g[18] = c.fc2 * y[9]  + c.fc3 * y[10];
    g[19] = c.fc4 * y[11] + c.fc5 * y[12];
    g[20] = c.fe0 * y[13] + c.fe1 * y[14];
    g[21] = c.fe2 * y[13] + c.fe3 * y[14];
    g[22] = c.fe4 * y[15] + c.fe5 * y[16];
    g[23] = c.fe6 * y[15] + c.fe7 * y[16];
}

__global__ __launch_bounds__(64, 1) void lp_kernel(
    const float* __restrict__ xtraj, const float* __restrict__ x,
    const float* __restrict__ ws_pr, const float* __restrict__ ws_v,
    float* __restrict__ out, int nprob)
{
    int p = blockIdx.x * 64 + threadIdx.x;
    if (p >= nprob) return;
    int b = p / 5, t = p % 5;
    const float* xt = xtraj + b * 45;
    const float* xb = x + b * 160;

    float r0 = xt[t], r1 = xt[5 + t];
    float ddr0 = xt[30 + t], ddr1 = xt[35 + t], ddr2 = xt[40 + t];

    float fc[8], fce[8], pe[4], vv[8], pr[4];
    #pragma unroll
    for (int i = 0; i < 8; ++i) fc[i] = xb[20 + 5 * i + t];
    #pragma unroll
    for (int i = 0; i < 4; ++i) pe[i] = xb[60 + 5 * i + t];
    #pragma unroll
    for (int i = 0; i < 8; ++i) fce[i] = xb[80 + 5 * i + t];
    #pragma unroll
    for (int i = 0; i < 8; ++i) vv[i] = ws_v[b * 40 + 5 * i + t];
    #pragma unroll
    for (int i = 0; i < 4; ++i) pr[i] = ws_pr[b * 20 + 5 * i + t];

    Coef co;
    co.c26 = pr[0] - r0;  co.c24 = r1 - pr[2];
    co.c27 = pr[1] - r0;  co.c25 = r1 - pr[3];
    co.c210 = pe[0] - r0; co.c28 = r1 - pe[2];
    co.c211 = pe[1] - r0; co.c29 = r1 - pe[3];
    co.v0 = vv[0]; co.v1 = vv[1]; co.v2 = vv[2];
    co.v3 = vv[3]; co.v4 = vv[4]; co.v5 = vv[5];
    co.fc0 = fc[0]; co.fc1 = fc[1]; co.fc2 = fc[2];
    co.fc3 = fc[3]; co.fc4 = fc[4]; co.fc5 = fc[5];
    co.fe0 = fce[0]; co.fe1 = fce[1]; co.fe2 = fce[2]; co.fe3 = fce[3];
    co.fe4 = fce[4]; co.fe5 = fce[5]; co.fe6 = fce[6]; co.fe7 = fce[7];

    // ---- spectral norm: 25 power iterations on A^T A ----
    float u[24], w[17], g[24];
    #pragma unroll
    for (int j = 0; j < 24; ++j) u[j] = 1.f;
    for (int it = 0; it < 25; ++it) {
        Az(co, u, w);
        ATy(co, w, u);
        float s = 0.f;
        #pragma unroll
        for (int j = 0; j < 24; ++j) s += u[j] * u[j];
        float inv = 1.f / (sqrtf(s) + 1e-12f);
        #pragma unroll
        for (int j = 0; j < 24; ++j) u[j] *= inv;
    }
    Az(co, u, w);
    float s2 = 0.f;
    #pragma unroll
    for (int e = 0; e < 17; ++e) s2 += w[e] * w[e];
    float L = sqrtf(s2);
    float tau = 0.9f / (L + 1e-8f);   // sig == tau

    // ---- PDHG ----
    float z[24], zb[24], y[17];
    #pragma unroll
    for (int j = 0; j < 24; ++j) { z[j] = 0.f; zb[j] = 0.f; }
    #pragma unroll
    for (int e = 0; e < 17; ++e) y[e] = 0.f;

    for (int it = 0; it < 400; ++it) {
        Az(co, zb, w);
        y[0] += tau * (w[0] - ddr0);
        y[1] += tau * (w[1] - ddr1);
        y[2] += tau * (w[2] - ddr2);
        y[3] += tau * w[3];
        y[4] += tau * w[4];
        y[5] += tau * (w[5] - 1.f);
        y[6] += tau * w[6];
        y[7] += tau * w[7];
        y[8] += tau * (w[8] - 1.f);
        #pragma unroll
        for (int e = 9; e < 17; ++e) y[e] += tau * w[e];

        ATy(co, y, g);
        #pragma unroll
        for (int j = 0; j < 24; ++j) {
            float gg = z[j] - tau * g[j];
            float zn;
            if (j >= 4 && j < 8) {                // L1 prox (soft threshold)
                float a = fmaxf(fabsf(gg) - tau, 0.f);
                zn = copysignf(a, gg);
            } else if (j >= 12) {                 // nonneg projection
                zn = fmaxf(gg, 0.f);
            } else {
                zn = gg;
            }
            zb[j] = 2.f * zn - z[j];
            z[j] = zn;
        }
    }

    // ---- write p, f portions of output ----
    float* ob = out + b * 100;
    #pragma unroll
    for (int i = 0; i < 4; ++i) {
        ob[i * 5 + t]      = 100.f * z[i];
        ob[20 + i * 5 + t] = 100.f * z[4 + i];
    }
}

extern "C" void kernel_launch(void* const* d_in, const int* in_sizes, int n_in,
                              void* d_out, int out_size, void* d_ws, size_t ws_size,
                              hipStream_t stream) {
    const float* xtraj = (const float*)d_in[0];
    const float* x     = (const float*)d_in[1];
    const float* x_img = (const float*)d_in[2];
    const float* cw1 = (const float*)d_in[3];
    const float* cb1 = (const float*)d_in[4];
    const float* cw2 = (const float*)d_in[5];
    const float* cb2 = (const float*)d_in[6];
    const float* w3  = (const float*)d_in[7];
    const float* b3  = (const float*)d_in[8];
    const float* w4  = (const float*)d_in[9];
    const float* b4  = (const float*)d_in[10];
    const float* pw1 = (const float*)d_in[11];
    const float* pb1 = (const float*)d_in[12];
    const float* pw2 = (const float*)d_in[13];
    const float* pb2 = (const float*)d_in[14];
    const float* pw3 = (const float*)d_in[15];
    const float* pb3 = (const float*)d_in[16];
    const float* vw1 = (const float*)d_in[17];
    const float* vb1 = (const float*)d_in[18];
    const float* vw2 = (const float*)d_in[19];
    const float* vb2 = (const float*)d_in[20];
    const float* vw3 = (const float*)d_in[21];
    const float* vb3 = (const float*)d_in[22];

    float* out = (float*)d_out;
    const int Bn = in_sizes[0] / 45;

    float* ws_pr = (float*)d_ws;             // Bn*20 floats
    float* ws_v  = ws_pr + (size_t)Bn * 20;  // Bn*40 floats

    enc_mlp_kernel<<<Bn, 256, 0, stream>>>(
        xtraj, x, x_img, cw1, cb1, cw2, cb2, w3, b3, w4, b4,
        pw1, pb1, pw2, pb2, pw3, pb3, vw1, vb1, vw2, vb2, vw3, vb3,
        out, ws_pr, ws_v);

    const int nprob = Bn * 5;
    lp_kernel<<<(nprob + 63) / 64, 64, 0, stream>>>(xtraj, x, ws_pr, ws_v, out, nprob);
}

// Round 3
// 282.460 us; speedup vs baseline: 2.0329x; 1.1770x over previous
//
#include <hip/hip_runtime.h>

// ---------------------------------------------------------------------------
// Kernel 1: per-sample encoder conv stack + dense layers + both MLPs.
// (unchanged from round 2 — passed, ~3x faster than round 1)
// ---------------------------------------------------------------------------
__global__ __launch_bounds__(256) void enc_mlp_kernel(
    const float* __restrict__ xtraj, const float* __restrict__ x,
    const float* __restrict__ x_img,
    const float* __restrict__ cw1, const float* __restrict__ cb1,
    const float* __restrict__ cw2, const float* __restrict__ cb2,
    const float* __restrict__ w3, const float* __restrict__ b3,
    const float* __restrict__ w4, const float* __restrict__ b4,
    const float* __restrict__ pw1, const float* __restrict__ pb1,
    const float* __restrict__ pw2, const float* __restrict__ pb2,
    const float* __restrict__ pw3, const float* __restrict__ pb3,
    const float* __restrict__ vw1, const float* __restrict__ vb1,
    const float* __restrict__ vw2, const float* __restrict__ vb2,
    const float* __restrict__ vw3, const float* __restrict__ vb3,
    float* __restrict__ out, float* __restrict__ ws_pr, float* __restrict__ ws_v)
{
    const int b = blockIdx.x;
    const int tid = threadIdx.x;

    __shared__ __align__(16) float s_img[2500];
    __shared__ __align__(16) float s_w2[5000];
    __shared__ __align__(16) float s_h1[4000];
    __shared__ __align__(16) float s_h2[320];
    __shared__ float s_hc[145];
    __shared__ float s_t1[152];
    __shared__ float s_m1[256];
    __shared__ float s_m2[256];

    const float* img = x_img + (size_t)b * 2500;
    for (int i = tid; i < 2500; i += 256) s_img[i] = img[i];
    for (int i = tid; i < 5000; i += 256) s_w2[i] = cw2[i];
    __syncthreads();

    // conv1 (11x11, 50->40) + maxpool2 + relu, register-tiled
    for (int qq = tid; qq < 400; qq += 256) {
        const int py = qq / 20, px = qq % 20;
        const int C = 2 * px;
        float acc0[10], acc1[10], acc2[10], acc3[10];
        #pragma unroll
        for (int oc = 0; oc < 10; ++oc) { acc0[oc] = 0.f; acc1[oc] = 0.f; acc2[oc] = 0.f; acc3[oc] = 0.f; }
        for (int r = 0; r < 12; ++r) {
            float v[12];
            #pragma unroll
            for (int j = 0; j < 6; ++j) {
                float2 t = *(const float2*)&s_img[(2 * py + r) * 50 + C + 2 * j];
                v[2 * j] = t.x; v[2 * j + 1] = t.y;
            }
            if (r < 11) {
                #pragma unroll
                for (int oc = 0; oc < 10; ++oc) {
                    #pragma unroll
                    for (int kx = 0; kx < 11; ++kx) {
                        float w0 = cw1[oc * 121 + r * 11 + kx];
                        acc0[oc] = fmaf(v[kx], w0, acc0[oc]);
                        acc1[oc] = fmaf(v[kx + 1], w0, acc1[oc]);
                    }
                }
            }
            if (r >= 1) {
                #pragma unroll
                for (int oc = 0; oc < 10; ++oc) {
                    #pragma unroll
                    for (int kx = 0; kx < 11; ++kx) {
                        float w1 = cw1[oc * 121 + (r - 1) * 11 + kx];
                        acc2[oc] = fmaf(v[kx], w1, acc2[oc]);
                        acc3[oc] = fmaf(v[kx + 1], w1, acc3[oc]);
                    }
                }
            }
        }
        #pragma unroll
        for (int oc = 0; oc < 10; ++oc) {
            float m = fmaxf(fmaxf(acc0[oc], acc1[oc]), fmaxf(acc2[oc], acc3[oc]));
            s_h1[oc * 400 + qq] = fmaxf(m + cb1[oc], 0.f);
        }
    }
    __syncthreads();

    // conv2 (5x5, 20->16, 10ic->20oc) + maxpool4 + relu, register-tiled
    for (int u = tid; u < 320; u += 256) {
        const int oc = u >> 4, cell = u & 15;
        const int R0 = (cell >> 2) * 4, C0 = (cell & 3) * 4;
        float acc[16];
        #pragma unroll
        for (int i = 0; i < 16; ++i) acc[i] = 0.f;
        for (int ic = 0; ic < 10; ++ic) {
            const float* hb = &s_h1[ic * 400];
            const float* wb = &s_w2[oc * 250 + ic * 25];
            float v[8][8];
            #pragma unroll
            for (int r = 0; r < 8; ++r) {
                float4 t0 = *(const float4*)&hb[(R0 + r) * 20 + C0];
                float4 t1 = *(const float4*)&hb[(R0 + r) * 20 + C0 + 4];
                v[r][0] = t0.x; v[r][1] = t0.y; v[r][2] = t0.z; v[r][3] = t0.w;
                v[r][4] = t1.x; v[r][5] = t1.y; v[r][6] = t1.z; v[r][7] = t1.w;
            }
            #pragma unroll
            for (int k = 0; k < 5; ++k) {
                #pragma unroll
                for (int kx = 0; kx < 5; ++kx) {
                    float wv = wb[k * 5 + kx];
                    #pragma unroll
                    for (int o = 0; o < 4; ++o) {
                        #pragma unroll
                        for (int c = 0; c < 4; ++c)
                            acc[o * 4 + c] = fmaf(v[o + k][c + kx], wv, acc[o * 4 + c]);
                    }
                }
            }
        }
        float m = acc[0];
        #pragma unroll
        for (int i = 1; i < 16; ++i) m = fmaxf(m, acc[i]);
        s_h2[u] = fmaxf(m + cb2[oc], 0.f);
    }
    __syncthreads();

    if (tid < 150) {
        const float* w = w3 + tid * 320;
        float acc = b3[tid];
        for (int k = 0; k < 320; ++k) acc = fmaf(s_h2[k], w[k], acc);
        s_t1[tid] = fmaxf(acc, 0.f);
    }
    __syncthreads();

    if (tid < 100) {
        const float* w = w4 + tid * 150;
        float acc = b4[tid];
        for (int k = 0; k < 150; ++k) acc = fmaf(s_t1[k], w[k], acc);
        s_hc[tid] = fmaxf(acc, 0.f);
    }
    if (tid >= 100 && tid < 145) s_hc[tid] = xtraj[b * 45 + (tid - 100)];
    __syncthreads();

    if (tid < 100) {
        const float* w = pw1 + tid * 145;
        float acc = pb1[tid];
        for (int k = 0; k < 145; ++k) acc = fmaf(s_hc[k], w[k], acc);
        s_m1[tid] = fmaxf(acc, 0.f);
    } else if (tid >= 128 && tid < 228) {
        int i = tid - 128;
        const float* w = vw1 + i * 145;
        float acc = vb1[i];
        for (int k = 0; k < 145; ++k) acc = fmaf(s_hc[k], w[k], acc);
        s_m1[tid] = fmaxf(acc, 0.f);
    }
    __syncthreads();

    if (tid < 100) {
        const float* w = pw2 + tid * 100;
        float acc = pb2[tid];
        for (int k = 0; k < 100; ++k) acc = fmaf(s_m1[k], w[k], acc);
        s_m2[tid] = fmaxf(acc, 0.f);
    } else if (tid >= 128 && tid < 228) {
        int i = tid - 128;
        const float* w = vw2 + i * 100;
        float acc = vb2[i];
        for (int k = 0; k < 100; ++k) acc = fmaf(s_m1[128 + k], w[k], acc);
        s_m2[tid] = fmaxf(acc, 0.f);
    }
    __syncthreads();

    if (tid < 20) {
        const float* w = pw3 + tid * 100;
        float acc = pb3[tid];
        for (int k = 0; k < 100; ++k) acc = fmaf(s_m2[k], w[k], acc);
        ws_pr[b * 20 + tid] = acc;
        out[b * 100 + 40 + tid] = 1000.f * (acc - x[b * 160 + tid]);
    } else if (tid >= 128 && tid < 168) {
        int i = tid - 128;
        const float* w = vw3 + i * 100;
        float acc = vb3[i];
        for (int k = 0; k < 100; ++k) acc = fmaf(s_m2[128 + k], w[k], acc);
        ws_v[b * 40 + i] = acc;
        out[b * 100 + 60 + i] = 1000.f * (acc - x[b * 160 + 120 + i]);
    }
}

// ---------------------------------------------------------------------------
// Kernel 2: lane-parallel PDHG. 32 lanes per problem (2 problems/wave).
// Lane j owns z[j]/zb[j] (j<24) and y[j] (j<17). Sparse matvecs are
// shuffle-gathers: A rows have <=8 nnz, A^T cols have <=3 nnz.
// Structure tables are compile-time; runtime coefficients come from a
// 31-slot per-problem value table built once in LDS.
//   slots: 0:0  1:1  2:-1  3..10:c24..c211  11..16:-v0..-v5
//          17..22:fc0..fc5  23..30:fe0..fe7
// ---------------------------------------------------------------------------
__device__ const signed char AZ_IDX[32][8] = {
    {4,5,6,7,8,9,0,0},{10,11,0,0,0,0,0,0},{4,5,6,7,8,9,10,11},
    {0,12,14,0,0,0,0,0},{2,12,14,0,0,0,0,0},{12,14,0,0,0,0,0,0},
    {1,13,15,0,0,0,0,0},{3,13,15,0,0,0,0,0},{13,15,0,0,0,0,0,0},
    {16,18,4,0,0,0,0,0},{16,18,6,0,0,0,0,0},{17,19,5,0,0,0,0,0},
    {17,19,7,0,0,0,0,0},{20,21,8,0,0,0,0,0},{20,21,10,0,0,0,0,0},
    {22,23,9,0,0,0,0,0},{22,23,11,0,0,0,0,0},
    {0},{0},{0},{0},{0},{0},{0},{0},{0},{0},{0},{0},{0},{0},{0}
};
__device__ const signed char AZ_SEL[32][8] = {
    {1,1,1,1,1,1,0,0},{1,1,0,0,0,0,0,0},{3,4,5,6,7,8,9,10},
    {1,11,13,0,0,0,0,0},{1,12,14,0,0,0,0,0},{1,1,0,0,0,0,0,0},
    {1,13,15,0,0,0,0,0},{1,14,16,0,0,0,0,0},{1,1,0,0,0,0,0,0},
    {17,19,2,0,0,0,0,0},{18,20,2,0,0,0,0,0},{19,21,2,0,0,0,0,0},
    {20,22,2,0,0,0,0,0},{23,25,2,0,0,0,0,0},{24,26,2,0,0,0,0,0},
    {27,29,2,0,0,0,0,0},{28,30,2,0,0,0,0,0},
    {0},{0},{0},{0},{0},{0},{0},{0},{0},{0},{0},{0},{0},{0},{0}
};
__device__ const signed char AT_IDX[32][3] = {
    {3,0,0},{6,0,0},{4,0,0},{7,0,0},
    {0,2,9},{0,2,11},{0,2,10},{0,2,12},{0,2,13},{0,2,15},{1,2,14},{1,2,16},
    {3,4,5},{6,7,8},{3,4,5},{6,7,8},
    {9,10,0},{11,12,0},{9,10,0},{11,12,0},
    {13,14,0},{13,14,0},{15,16,0},{15,16,0},
    {0},{0},{0},{0},{0},{0},{0},{0}
};
__device__ const signed char AT_SEL[32][3] = {
    {1,0,0},{1,0,0},{1,0,0},{1,0,0},
    {1,3,2},{1,4,2},{1,5,2},{1,6,2},{1,7,2},{1,8,2},{1,9,2},{1,10,2},
    {11,12,1},{13,14,1},{13,14,1},{15,16,1},
    {17,18,0},{19,20,0},{19,20,0},{21,22,0},
    {23,24,0},{25,26,0},{27,28,0},{29,30,0},
    {0},{0},{0},{0},{0},{0},{0},{0}
};

__global__ __launch_bounds__(64) void lp_kernel(
    const float* __restrict__ xtraj, const float* __restrict__ x,
    const float* __restrict__ ws_pr, const float* __restrict__ ws_v,
    float* __restrict__ out, int nprob)
{
    const int g = threadIdx.x >> 5;         // group within block (0..1)
    const int l = threadIdx.x & 31;         // lane within group
    const int p = blockIdx.x * 2 + g;       // problem id
    const int pc = p < nprob ? p : nprob - 1;
    const int b = pc / 5, t = pc % 5;
    const float* xt = xtraj + b * 45;
    const float* xb = x + b * 160;

    __shared__ float s_val[2][32];

    // ---- build 31-slot value table (once) ----
    {
        float val = 0.f;
        if (l == 1) val = 1.f;
        else if (l == 2) val = -1.f;
        else if (l >= 3 && l <= 10) {
            float r0 = xt[t], r1 = xt[5 + t];
            switch (l) {
                case 3:  val = r1 - ws_pr[b * 20 + 10 + t]; break;  // c24
                case 4:  val = r1 - ws_pr[b * 20 + 15 + t]; break;  // c25
                case 5:  val = ws_pr[b * 20 + 0 + t] - r0;  break;  // c26
                case 6:  val = ws_pr[b * 20 + 5 + t] - r0;  break;  // c27
                case 7:  val = r1 - xb[60 + 10 + t]; break;         // c28
                case 8:  val = r1 - xb[60 + 15 + t]; break;         // c29
                case 9:  val = xb[60 + 0 + t] - r0;  break;         // c210
                default: val = xb[60 + 5 + t] - r0;  break;         // c211
            }
        }
        else if (l >= 11 && l <= 16) val = -ws_v[b * 40 + 5 * (l - 11) + t];
        else if (l >= 17 && l <= 22) val = xb[20 + 5 * (l - 17) + t];
        else if (l >= 23 && l <= 30) val = xb[80 + 5 * (l - 23) + t];
        s_val[g][l] = val;
    }
    __syncthreads();

    // ---- per-lane coefficient/index registers ----
    float cfA[8]; int ixA[8];
    #pragma unroll
    for (int k = 0; k < 8; ++k) {
        ixA[k] = AZ_IDX[l][k];
        cfA[k] = s_val[g][(int)AZ_SEL[l][k]];
    }
    float cfT[3]; int ixT[3];
    #pragma unroll
    for (int k = 0; k < 3; ++k) {
        ixT[k] = AT_IDX[l][k];
        cfT[k] = s_val[g][(int)AT_SEL[l][k]];
    }
    float bb = 0.f;
    if (l == 0) bb = xt[30 + t];
    else if (l == 1) bb = xt[35 + t];
    else if (l == 2) bb = xt[40 + t];
    else if (l == 5 || l == 8) bb = 1.f;

    const bool isF  = (l >= 4 && l < 8);
    const bool isNN = (l >= 12);

    // ---- spectral norm: 25 power iterations on A^T A ----
    float u = (l < 24) ? 1.f : 0.f;
    for (int it = 0; it < 25; ++it) {
        float w = 0.f;
        #pragma unroll
        for (int k = 0; k < 8; ++k) w = fmaf(cfA[k], __shfl(u, ixA[k], 32), w);
        float nu = 0.f;
        #pragma unroll
        for (int k = 0; k < 3; ++k) nu = fmaf(cfT[k], __shfl(w, ixT[k], 32), nu);
        float s = (l < 24) ? nu * nu : 0.f;
        s += __shfl_xor(s, 16, 32); s += __shfl_xor(s, 8, 32);
        s += __shfl_xor(s, 4, 32);  s += __shfl_xor(s, 2, 32);
        s += __shfl_xor(s, 1, 32);
        u = nu / (sqrtf(s) + 1e-12f);
    }
    float tau;
    {
        float w = 0.f;
        #pragma unroll
        for (int k = 0; k < 8; ++k) w = fmaf(cfA[k], __shfl(u, ixA[k], 32), w);
        float s2 = (l < 17) ? w * w : 0.f;
        s2 += __shfl_xor(s2, 16, 32); s2 += __shfl_xor(s2, 8, 32);
        s2 += __shfl_xor(s2, 4, 32);  s2 += __shfl_xor(s2, 2, 32);
        s2 += __shfl_xor(s2, 1, 32);
        tau = 0.9f / (sqrtf(s2) + 1e-8f);
    }

    // ---- PDHG: 400 iterations ----
    float zv = 0.f, zbv = 0.f, yv = 0.f;
    for (int it = 0; it < 400; ++it) {
        float w = 0.f;
        #pragma unroll
        for (int k = 0; k < 8; ++k) w = fmaf(cfA[k], __shfl(zbv, ixA[k], 32), w);
        yv = fmaf(tau, w - bb, yv);

        float gv = 0.f;
        #pragma unroll
        for (int k = 0; k < 3; ++k) gv = fmaf(cfT[k], __shfl(yv, ixT[k], 32), gv);

        float gg = fmaf(-tau, gv, zv);
        float st = copysignf(fmaxf(fabsf(gg) - tau, 0.f), gg);
        float nn = fmaxf(gg, 0.f);
        float zn = isF ? st : (isNN ? nn : gg);
        zbv = 2.f * zn - zv;
        zv = zn;
    }

    // ---- write p (z0..z3) and f (z4..z7) ----
    if (p < nprob) {
        float* ob = out + b * 100;
        if (l < 4)      ob[l * 5 + t]            = 100.f * zv;
        else if (l < 8) ob[20 + (l - 4) * 5 + t] = 100.f * zv;
    }
}

extern "C" void kernel_launch(void* const* d_in, const int* in_sizes, int n_in,
                              void* d_out, int out_size, void* d_ws, size_t ws_size,
                              hipStream_t stream) {
    const float* xtraj = (const float*)d_in[0];
    const float* x     = (const float*)d_in[1];
    const float* x_img = (const float*)d_in[2];
    const float* cw1 = (const float*)d_in[3];
    const float* cb1 = (const float*)d_in[4];
    const float* cw2 = (const float*)d_in[5];
    const float* cb2 = (const float*)d_in[6];
    const float* w3  = (const float*)d_in[7];
    const float* b3  = (const float*)d_in[8];
    const float* w4  = (const float*)d_in[9];
    const float* b4  = (const float*)d_in[10];
    const float* pw1 = (const float*)d_in[11];
    const float* pb1 = (const float*)d_in[12];
    const float* pw2 = (const float*)d_in[13];
    const float* pb2 = (const float*)d_in[14];
    const float* pw3 = (const float*)d_in[15];
    const float* pb3 = (const float*)d_in[16];
    const float* vw1 = (const float*)d_in[17];
    const float* vb1 = (const float*)d_in[18];
    const float* vw2 = (const float*)d_in[19];
    const float* vb2 = (const float*)d_in[20];
    const float* vw3 = (const float*)d_in[21];
    const float* vb3 = (const float*)d_in[22];

    float* out = (float*)d_out;
    const int Bn = in_sizes[0] / 45;

    float* ws_pr = (float*)d_ws;             // Bn*20 floats
    float* ws_v  = ws_pr + (size_t)Bn * 20;  // Bn*40 floats

    enc_mlp_kernel<<<Bn, 256, 0, stream>>>(
        xtraj, x, x_img, cw1, cb1, cw2, cb2, w3, b3, w4, b4,
        pw1, pb1, pw2, pb2, pw3, pb3, vw1, vb1, vw2, vb2, vw3, vb3,
        out, ws_pr, ws_v);

    const int nprob = Bn * 5;
    lp_kernel<<<(nprob + 1) / 2, 64, 0, stream>>>(xtraj, x, ws_pr, ws_v, out, nprob);
}

// Round 4
// 275.391 us; speedup vs baseline: 2.0851x; 1.0257x over previous
//
#include <hip/hip_runtime.h>

// ---------------------------------------------------------------------------
// K1: conv1 (11x11, 50->40) + maxpool2 + relu, 4 blocks per sample.
// Block = 128 threads; block (b, c) computes pooled rows py in [5c, 5c+5).
// Each thread: one 2x2 pre-pool quad, all 10 output channels (40 accs).
// Writes h1[b][oc][20][20] to workspace.
// ---------------------------------------------------------------------------
__global__ __launch_bounds__(128) void conv1_kernel(
    const float* __restrict__ x_img, const float* __restrict__ cw1,
    const float* __restrict__ cb1, float* __restrict__ h1)
{
    const int blk = blockIdx.x;
    const int b = blk >> 2;
    const int c = blk & 3;
    const int tid = threadIdx.x;

    __shared__ __align__(16) float s_img[1000];   // image rows [10c, 10c+20) x 50

    const float* img = x_img + (size_t)b * 2500 + (size_t)(10 * c) * 50;
    for (int i = tid; i < 1000; i += 128) s_img[i] = img[i];
    __syncthreads();

    if (tid < 100) {
        const int ly = tid / 20, px = tid % 20;   // local pooled row, col
        const int py = 5 * c + ly;                // global pooled row
        const int C = 2 * px;
        float acc0[10], acc1[10], acc2[10], acc3[10];
        #pragma unroll
        for (int oc = 0; oc < 10; ++oc) { acc0[oc] = 0.f; acc1[oc] = 0.f; acc2[oc] = 0.f; acc3[oc] = 0.f; }
        for (int r = 0; r < 12; ++r) {            // local image rows 2ly + r
            float v[12];
            #pragma unroll
            for (int j = 0; j < 6; ++j) {
                float2 t = *(const float2*)&s_img[(2 * ly + r) * 50 + C + 2 * j];
                v[2 * j] = t.x; v[2 * j + 1] = t.y;
            }
            if (r < 11) {                         // out-row 2py (k = r)
                #pragma unroll
                for (int oc = 0; oc < 10; ++oc) {
                    #pragma unroll
                    for (int kx = 0; kx < 11; ++kx) {
                        float w0 = cw1[oc * 121 + r * 11 + kx];
                        acc0[oc] = fmaf(v[kx], w0, acc0[oc]);
                        acc1[oc] = fmaf(v[kx + 1], w0, acc1[oc]);
                    }
                }
            }
            if (r >= 1) {                         // out-row 2py+1 (k = r-1)
                #pragma unroll
                for (int oc = 0; oc < 10; ++oc) {
                    #pragma unroll
                    for (int kx = 0; kx < 11; ++kx) {
                        float w1 = cw1[oc * 121 + (r - 1) * 11 + kx];
                        acc2[oc] = fmaf(v[kx], w1, acc2[oc]);
                        acc3[oc] = fmaf(v[kx + 1], w1, acc3[oc]);
                    }
                }
            }
        }
        float* hb = h1 + (size_t)b * 4000 + py * 20 + px;
        #pragma unroll
        for (int oc = 0; oc < 10; ++oc) {
            float m = fmaxf(fmaxf(acc0[oc], acc1[oc]), fmaxf(acc2[oc], acc3[oc]));
            hb[oc * 400] = fmaxf(m + cb1[oc], 0.f);
        }
    }
}

// ---------------------------------------------------------------------------
// K2: conv2 (5x5, 20->16, 10ic->20oc) + maxpool4 + relu + dense stack + MLPs.
// One block (320 threads) per sample: conv2's 320 pooled outputs in ONE pass.
// ---------------------------------------------------------------------------
__global__ __launch_bounds__(320) void head_kernel(
    const float* __restrict__ xtraj, const float* __restrict__ x,
    const float* __restrict__ h1g,
    const float* __restrict__ cw2, const float* __restrict__ cb2,
    const float* __restrict__ w3, const float* __restrict__ b3,
    const float* __restrict__ w4, const float* __restrict__ b4,
    const float* __restrict__ pw1, const float* __restrict__ pb1,
    const float* __restrict__ pw2, const float* __restrict__ pb2,
    const float* __restrict__ pw3, const float* __restrict__ pb3,
    const float* __restrict__ vw1, const float* __restrict__ vb1,
    const float* __restrict__ vw2, const float* __restrict__ vb2,
    const float* __restrict__ vw3, const float* __restrict__ vb3,
    float* __restrict__ out, float* __restrict__ ws_pr, float* __restrict__ ws_v)
{
    const int b = blockIdx.x;
    const int tid = threadIdx.x;

    __shared__ __align__(16) float s_h1[4000];
    __shared__ __align__(16) float s_w2[5000];
    __shared__ __align__(16) float s_h2[320];
    __shared__ float s_hc[145];
    __shared__ float s_t1[152];
    __shared__ float s_m1[256];
    __shared__ float s_m2[256];

    // ---- stage h1 + conv2 weights (float4) ----
    {
        const float4* src = (const float4*)(h1g + (size_t)b * 4000);
        float4* dst = (float4*)s_h1;
        for (int i = tid; i < 1000; i += 320) dst[i] = src[i];
        const float4* wsrc = (const float4*)cw2;
        float4* wdst = (float4*)s_w2;
        for (int i = tid; i < 1250; i += 320) wdst[i] = wsrc[i];
    }
    __syncthreads();

    // ---- conv2 + maxpool4 + relu: one pooled output per thread ----
    {
        const int oc = tid >> 4, cell = tid & 15;
        const int R0 = (cell >> 2) * 4, C0 = (cell & 3) * 4;
        float acc[16];
        #pragma unroll
        for (int i = 0; i < 16; ++i) acc[i] = 0.f;
        for (int ic = 0; ic < 10; ++ic) {
            const float* hb = &s_h1[ic * 400];
            const float* wb = &s_w2[oc * 250 + ic * 25];
            float v[8][8];
            #pragma unroll
            for (int r = 0; r < 8; ++r) {
                float4 t0 = *(const float4*)&hb[(R0 + r) * 20 + C0];
                float4 t1 = *(const float4*)&hb[(R0 + r) * 20 + C0 + 4];
                v[r][0] = t0.x; v[r][1] = t0.y; v[r][2] = t0.z; v[r][3] = t0.w;
                v[r][4] = t1.x; v[r][5] = t1.y; v[r][6] = t1.z; v[r][7] = t1.w;
            }
            #pragma unroll
            for (int k = 0; k < 5; ++k) {
                #pragma unroll
                for (int kx = 0; kx < 5; ++kx) {
                    float wv = wb[k * 5 + kx];
                    #pragma unroll
                    for (int o = 0; o < 4; ++o) {
                        #pragma unroll
                        for (int cc = 0; cc < 4; ++cc)
                            acc[o * 4 + cc] = fmaf(v[o + k][cc + kx], wv, acc[o * 4 + cc]);
                    }
                }
            }
        }
        float m = acc[0];
        #pragma unroll
        for (int i = 1; i < 16; ++i) m = fmaxf(m, acc[i]);
        s_h2[tid] = fmaxf(m + cb2[oc], 0.f);     // flatten: oc*16 + py*4 + px
    }
    __syncthreads();

    // ---- dense 320 -> 150, relu ----
    if (tid < 150) {
        const float* w = w3 + tid * 320;
        float a0 = b3[tid], a1 = 0.f, a2 = 0.f, a3 = 0.f;
        for (int k = 0; k < 320; k += 4) {
            a0 = fmaf(s_h2[k],     w[k],     a0);
            a1 = fmaf(s_h2[k + 1], w[k + 1], a1);
            a2 = fmaf(s_h2[k + 2], w[k + 2], a2);
            a3 = fmaf(s_h2[k + 3], w[k + 3], a3);
        }
        s_t1[tid] = fmaxf((a0 + a1) + (a2 + a3), 0.f);
    }
    __syncthreads();

    // ---- dense 150 -> 100, relu -> s_hc[0:100]; concat xtraj ----
    if (tid < 100) {
        const float* w = w4 + tid * 150;
        float a0 = b4[tid], a1 = 0.f;
        for (int k = 0; k < 150; k += 2) {
            a0 = fmaf(s_t1[k],     w[k],     a0);
            a1 = fmaf(s_t1[k + 1], w[k + 1], a1);
        }
        s_hc[tid] = fmaxf(a0 + a1, 0.f);
    }
    if (tid >= 100 && tid < 145) s_hc[tid] = xtraj[b * 45 + (tid - 100)];
    __syncthreads();

    // ---- two MLPs in parallel: p-net threads 0..99, v-net threads 128..227 ----
    if (tid < 100) {
        const float* w = pw1 + tid * 145;
        float acc = pb1[tid];
        for (int k = 0; k < 145; ++k) acc = fmaf(s_hc[k], w[k], acc);
        s_m1[tid] = fmaxf(acc, 0.f);
    } else if (tid >= 128 && tid < 228) {
        int i = tid - 128;
        const float* w = vw1 + i * 145;
        float acc = vb1[i];
        for (int k = 0; k < 145; ++k) acc = fmaf(s_hc[k], w[k], acc);
        s_m1[tid] = fmaxf(acc, 0.f);
    }
    __syncthreads();

    if (tid < 100) {
        const float* w = pw2 + tid * 100;
        float acc = pb2[tid];
        for (int k = 0; k < 100; ++k) acc = fmaf(s_m1[k], w[k], acc);
        s_m2[tid] = fmaxf(acc, 0.f);
    } else if (tid >= 128 && tid < 228) {
        int i = tid - 128;
        const float* w = vw2 + i * 100;
        float acc = vb2[i];
        for (int k = 0; k < 100; ++k) acc = fmaf(s_m1[128 + k], w[k], acc);
        s_m2[tid] = fmaxf(acc, 0.f);
    }
    __syncthreads();

    if (tid < 20) {
        const float* w = pw3 + tid * 100;
        float acc = pb3[tid];
        for (int k = 0; k < 100; ++k) acc = fmaf(s_m2[k], w[k], acc);
        ws_pr[b * 20 + tid] = acc;
        out[b * 100 + 40 + tid] = 1000.f * (acc - x[b * 160 + tid]);
    } else if (tid >= 128 && tid < 168) {
        int i = tid - 128;
        const float* w = vw3 + i * 100;
        float acc = vb3[i];
        for (int k = 0; k < 100; ++k) acc = fmaf(s_m2[128 + k], w[k], acc);
        ws_v[b * 40 + i] = acc;
        out[b * 100 + 60 + i] = 1000.f * (acc - x[b * 160 + 120 + i]);
    }
}

// ---------------------------------------------------------------------------
// K3: lane-parallel PDHG. 32 lanes per problem (2 problems/wave).
// (unchanged from round 3 — passed, absmax 0.0156)
// ---------------------------------------------------------------------------
__device__ const signed char AZ_IDX[32][8] = {
    {4,5,6,7,8,9,0,0},{10,11,0,0,0,0,0,0},{4,5,6,7,8,9,10,11},
    {0,12,14,0,0,0,0,0},{2,12,14,0,0,0,0,0},{12,14,0,0,0,0,0,0},
    {1,13,15,0,0,0,0,0},{3,13,15,0,0,0,0,0},{13,15,0,0,0,0,0,0},
    {16,18,4,0,0,0,0,0},{16,18,6,0,0,0,0,0},{17,19,5,0,0,0,0,0},
    {17,19,7,0,0,0,0,0},{20,21,8,0,0,0,0,0},{20,21,10,0,0,0,0,0},
    {22,23,9,0,0,0,0,0},{22,23,11,0,0,0,0,0},
    {0},{0},{0},{0},{0},{0},{0},{0},{0},{0},{0},{0},{0},{0},{0}
};
__device__ const signed char AZ_SEL[32][8] = {
    {1,1,1,1,1,1,0,0},{1,1,0,0,0,0,0,0},{3,4,5,6,7,8,9,10},
    {1,11,13,0,0,0,0,0},{1,12,14,0,0,0,0,0},{1,1,0,0,0,0,0,0},
    {1,13,15,0,0,0,0,0},{1,14,16,0,0,0,0,0},{1,1,0,0,0,0,0,0},
    {17,19,2,0,0,0,0,0},{18,20,2,0,0,0,0,0},{19,21,2,0,0,0,0,0},
    {20,22,2,0,0,0,0,0},{23,25,2,0,0,0,0,0},{24,26,2,0,0,0,0,0},
    {27,29,2,0,0,0,0,0},{28,30,2,0,0,0,0,0},
    {0},{0},{0},{0},{0},{0},{0},{0},{0},{0},{0},{0},{0},{0},{0}
};
__device__ const signed char AT_IDX[32][3] = {
    {3,0,0},{6,0,0},{4,0,0},{7,0,0},
    {0,2,9},{0,2,11},{0,2,10},{0,2,12},{0,2,13},{0,2,15},{1,2,14},{1,2,16},
    {3,4,5},{6,7,8},{3,4,5},{6,7,8},
    {9,10,0},{11,12,0},{9,10,0},{11,12,0},
    {13,14,0},{13,14,0},{15,16,0},{15,16,0},
    {0},{0},{0},{0},{0},{0},{0},{0}
};
__device__ const signed char AT_SEL[32][3] = {
    {1,0,0},{1,0,0},{1,0,0},{1,0,0},
    {1,3,2},{1,4,2},{1,5,2},{1,6,2},{1,7,2},{1,8,2},{1,9,2},{1,10,2},
    {11,12,1},{13,14,1},{13,14,1},{15,16,1},
    {17,18,0},{19,20,0},{19,20,0},{21,22,0},
    {23,24,0},{25,26,0},{27,28,0},{29,30,0},
    {0},{0},{0},{0},{0},{0},{0},{0}
};

__global__ __launch_bounds__(64) void lp_kernel(
    const float* __restrict__ xtraj, const float* __restrict__ x,
    const float* __restrict__ ws_pr, const float* __restrict__ ws_v,
    float* __restrict__ out, int nprob)
{
    const int g = threadIdx.x >> 5;
    const int l = threadIdx.x & 31;
    const int p = blockIdx.x * 2 + g;
    const int pc = p < nprob ? p : nprob - 1;
    const int b = pc / 5, t = pc % 5;
    const float* xt = xtraj + b * 45;
    const float* xb = x + b * 160;

    __shared__ float s_val[2][32];

    {
        float val = 0.f;
        if (l == 1) val = 1.f;
        else if (l == 2) val = -1.f;
        else if (l >= 3 && l <= 10) {
            float r0 = xt[t], r1 = xt[5 + t];
            switch (l) {
                case 3:  val = r1 - ws_pr[b * 20 + 10 + t]; break;
                case 4:  val = r1 - ws_pr[b * 20 + 15 + t]; break;
                case 5:  val = ws_pr[b * 20 + 0 + t] - r0;  break;
                case 6:  val = ws_pr[b * 20 + 5 + t] - r0;  break;
                case 7:  val = r1 - xb[60 + 10 + t]; break;
                case 8:  val = r1 - xb[60 + 15 + t]; break;
                case 9:  val = xb[60 + 0 + t] - r0;  break;
                default: val = xb[60 + 5 + t] - r0;  break;
            }
        }
        else if (l >= 11 && l <= 16) val = -ws_v[b * 40 + 5 * (l - 11) + t];
        else if (l >= 17 && l <= 22) val = xb[20 + 5 * (l - 17) + t];
        else if (l >= 23 && l <= 30) val = xb[80 + 5 * (l - 23) + t];
        s_val[g][l] = val;
    }
    __syncthreads();

    float cfA[8]; int ixA[8];
    #pragma unroll
    for (int k = 0; k < 8; ++k) {
        ixA[k] = AZ_IDX[l][k];
        cfA[k] = s_val[g][(int)AZ_SEL[l][k]];
    }
    float cfT[3]; int ixT[3];
    #pragma unroll
    for (int k = 0; k < 3; ++k) {
        ixT[k] = AT_IDX[l][k];
        cfT[k] = s_val[g][(int)AT_SEL[l][k]];
    }
    float bb = 0.f;
    if (l == 0) bb = xt[30 + t];
    else if (l == 1) bb = xt[35 + t];
    else if (l == 2) bb = xt[40 + t];
    else if (l == 5 || l == 8) bb = 1.f;

    const bool isF  = (l >= 4 && l < 8);
    const bool isNN = (l >= 12);

    float u = (l < 24) ? 1.f : 0.f;
    for (int it = 0; it < 25; ++it) {
        float w = 0.f;
        #pragma unroll
        for (int k = 0; k < 8; ++k) w = fmaf(cfA[k], __shfl(u, ixA[k], 32), w);
        float nu = 0.f;
        #pragma unroll
        for (int k = 0; k < 3; ++k) nu = fmaf(cfT[k], __shfl(w, ixT[k], 32), nu);
        float s = (l < 24) ? nu * nu : 0.f;
        s += __shfl_xor(s, 16, 32); s += __shfl_xor(s, 8, 32);
        s += __shfl_xor(s, 4, 32);  s += __shfl_xor(s, 2, 32);
        s += __shfl_xor(s, 1, 32);
        u = nu / (sqrtf(s) + 1e-12f);
    }
    float tau;
    {
        float w = 0.f;
        #pragma unroll
        for (int k = 0; k < 8; ++k) w = fmaf(cfA[k], __shfl(u, ixA[k], 32), w);
        float s2 = (l < 17) ? w * w : 0.f;
        s2 += __shfl_xor(s2, 16, 32); s2 += __shfl_xor(s2, 8, 32);
        s2 += __shfl_xor(s2, 4, 32);  s2 += __shfl_xor(s2, 2, 32);
        s2 += __shfl_xor(s2, 1, 32);
        tau = 0.9f / (sqrtf(s2) + 1e-8f);
    }

    float zv = 0.f, zbv = 0.f, yv = 0.f;
    for (int it = 0; it < 400; ++it) {
        float w = 0.f;
        #pragma unroll
        for (int k = 0; k < 8; ++k) w = fmaf(cfA[k], __shfl(zbv, ixA[k], 32), w);
        yv = fmaf(tau, w - bb, yv);

        float gv = 0.f;
        #pragma unroll
        for (int k = 0; k < 3; ++k) gv = fmaf(cfT[k], __shfl(yv, ixT[k], 32), gv);

        float gg = fmaf(-tau, gv, zv);
        float st = copysignf(fmaxf(fabsf(gg) - tau, 0.f), gg);
        float nn = fmaxf(gg, 0.f);
        float zn = isF ? st : (isNN ? nn : gg);
        zbv = 2.f * zn - zv;
        zv = zn;
    }

    if (p < nprob) {
        float* ob = out + b * 100;
        if (l < 4)      ob[l * 5 + t]            = 100.f * zv;
        else if (l < 8) ob[20 + (l - 4) * 5 + t] = 100.f * zv;
    }
}

extern "C" void kernel_launch(void* const* d_in, const int* in_sizes, int n_in,
                              void* d_out, int out_size, void* d_ws, size_t ws_size,
                              hipStream_t stream) {
    const float* xtraj = (const float*)d_in[0];
    const float* x     = (const float*)d_in[1];
    const float* x_img = (const float*)d_in[2];
    const float* cw1 = (const float*)d_in[3];
    const float* cb1 = (const float*)d_in[4];
    const float* cw2 = (const float*)d_in[5];
    const float* cb2 = (const float*)d_in[6];
    const float* w3  = (const float*)d_in[7];
    const float* b3  = (const float*)d_in[8];
    const float* w4  = (const float*)d_in[9];
    const float* b4  = (const float*)d_in[10];
    const float* pw1 = (const float*)d_in[11];
    const float* pb1 = (const float*)d_in[12];
    const float* pw2 = (const float*)d_in[13];
    const float* pb2 = (const float*)d_in[14];
    const float* pw3 = (const float*)d_in[15];
    const float* pb3 = (const float*)d_in[16];
    const float* vw1 = (const float*)d_in[17];
    const float* vb1 = (const float*)d_in[18];
    const float* vw2 = (const float*)d_in[19];
    const float* vb2 = (const float*)d_in[20];
    const float* vw3 = (const float*)d_in[21];
    const float* vb3 = (const float*)d_in[22];

    float* out = (float*)d_out;
    const int Bn = in_sizes[0] / 45;

    float* ws_pr = (float*)d_ws;              // Bn*20 floats
    float* ws_v  = ws_pr + (size_t)Bn * 20;   // Bn*40 floats
    float* ws_h1 = ws_v + (size_t)Bn * 40;    // Bn*4000 floats (~8.2 MB)

    conv1_kernel<<<Bn * 4, 128, 0, stream>>>(x_img, cw1, cb1, ws_h1);

    head_kernel<<<Bn, 320, 0, stream>>>(
        xtraj, x, ws_h1, cw2, cb2, w3, b3, w4, b4,
        pw1, pb1, pw2, pb2, pw3, pb3, vw1, vb1, vw2, vb2, vw3, vb3,
        out, ws_pr, ws_v);

    const int nprob = Bn * 5;
    lp_kernel<<<(nprob + 1) / 2, 64, 0, stream>>>(xtraj, x, ws_pr, ws_v, out, nprob);
}

// Round 5
// 267.987 us; speedup vs baseline: 2.1427x; 1.0276x over previous
//
#include <hip/hip_runtime.h>

// ---------------------------------------------------------------------------
// K1: conv1 (11x11, 50->40) + maxpool2 + relu, 4 blocks per sample.
// (unchanged from round 4)
// ---------------------------------------------------------------------------
__global__ __launch_bounds__(128) void conv1_kernel(
    const float* __restrict__ x_img, const float* __restrict__ cw1,
    const float* __restrict__ cb1, float* __restrict__ h1)
{
    const int blk = blockIdx.x;
    const int b = blk >> 2;
    const int c = blk & 3;
    const int tid = threadIdx.x;

    __shared__ __align__(16) float s_img[1000];

    const float* img = x_img + (size_t)b * 2500 + (size_t)(10 * c) * 50;
    for (int i = tid; i < 1000; i += 128) s_img[i] = img[i];
    __syncthreads();

    if (tid < 100) {
        const int ly = tid / 20, px = tid % 20;
        const int py = 5 * c + ly;
        const int C = 2 * px;
        float acc0[10], acc1[10], acc2[10], acc3[10];
        #pragma unroll
        for (int oc = 0; oc < 10; ++oc) { acc0[oc] = 0.f; acc1[oc] = 0.f; acc2[oc] = 0.f; acc3[oc] = 0.f; }
        for (int r = 0; r < 12; ++r) {
            float v[12];
            #pragma unroll
            for (int j = 0; j < 6; ++j) {
                float2 t = *(const float2*)&s_img[(2 * ly + r) * 50 + C + 2 * j];
                v[2 * j] = t.x; v[2 * j + 1] = t.y;
            }
            if (r < 11) {
                #pragma unroll
                for (int oc = 0; oc < 10; ++oc) {
                    #pragma unroll
                    for (int kx = 0; kx < 11; ++kx) {
                        float w0 = cw1[oc * 121 + r * 11 + kx];
                        acc0[oc] = fmaf(v[kx], w0, acc0[oc]);
                        acc1[oc] = fmaf(v[kx + 1], w0, acc1[oc]);
                    }
                }
            }
            if (r >= 1) {
                #pragma unroll
                for (int oc = 0; oc < 10; ++oc) {
                    #pragma unroll
                    for (int kx = 0; kx < 11; ++kx) {
                        float w1 = cw1[oc * 121 + (r - 1) * 11 + kx];
                        acc2[oc] = fmaf(v[kx], w1, acc2[oc]);
                        acc3[oc] = fmaf(v[kx + 1], w1, acc3[oc]);
                    }
                }
            }
        }
        float* hb = h1 + (size_t)b * 4000 + py * 20 + px;
        #pragma unroll
        for (int oc = 0; oc < 10; ++oc) {
            float m = fmaxf(fmaxf(acc0[oc], acc1[oc]), fmaxf(acc2[oc], acc3[oc]));
            hb[oc * 400] = fmaxf(m + cb1[oc], 0.f);
        }
    }
}

// ---------------------------------------------------------------------------
// K2: conv2 + maxpool4 + relu + dense stack + MLPs. (unchanged from round 4)
// ---------------------------------------------------------------------------
__global__ __launch_bounds__(320) void head_kernel(
    const float* __restrict__ xtraj, const float* __restrict__ x,
    const float* __restrict__ h1g,
    const float* __restrict__ cw2, const float* __restrict__ cb2,
    const float* __restrict__ w3, const float* __restrict__ b3,
    const float* __restrict__ w4, const float* __restrict__ b4,
    const float* __restrict__ pw1, const float* __restrict__ pb1,
    const float* __restrict__ pw2, const float* __restrict__ pb2,
    const float* __restrict__ pw3, const float* __restrict__ pb3,
    const float* __restrict__ vw1, const float* __restrict__ vb1,
    const float* __restrict__ vw2, const float* __restrict__ vb2,
    const float* __restrict__ vw3, const float* __restrict__ vb3,
    float* __restrict__ out, float* __restrict__ ws_pr, float* __restrict__ ws_v)
{
    const int b = blockIdx.x;
    const int tid = threadIdx.x;

    __shared__ __align__(16) float s_h1[4000];
    __shared__ __align__(16) float s_w2[5000];
    __shared__ __align__(16) float s_h2[320];
    __shared__ float s_hc[145];
    __shared__ float s_t1[152];
    __shared__ float s_m1[256];
    __shared__ float s_m2[256];

    {
        const float4* src = (const float4*)(h1g + (size_t)b * 4000);
        float4* dst = (float4*)s_h1;
        for (int i = tid; i < 1000; i += 320) dst[i] = src[i];
        const float4* wsrc = (const float4*)cw2;
        float4* wdst = (float4*)s_w2;
        for (int i = tid; i < 1250; i += 320) wdst[i] = wsrc[i];
    }
    __syncthreads();

    {
        const int oc = tid >> 4, cell = tid & 15;
        const int R0 = (cell >> 2) * 4, C0 = (cell & 3) * 4;
        float acc[16];
        #pragma unroll
        for (int i = 0; i < 16; ++i) acc[i] = 0.f;
        for (int ic = 0; ic < 10; ++ic) {
            const float* hb = &s_h1[ic * 400];
            const float* wb = &s_w2[oc * 250 + ic * 25];
            float v[8][8];
            #pragma unroll
            for (int r = 0; r < 8; ++r) {
                float4 t0 = *(const float4*)&hb[(R0 + r) * 20 + C0];
                float4 t1 = *(const float4*)&hb[(R0 + r) * 20 + C0 + 4];
                v[r][0] = t0.x; v[r][1] = t0.y; v[r][2] = t0.z; v[r][3] = t0.w;
                v[r][4] = t1.x; v[r][5] = t1.y; v[r][6] = t1.z; v[r][7] = t1.w;
            }
            #pragma unroll
            for (int k = 0; k < 5; ++k) {
                #pragma unroll
                for (int kx = 0; kx < 5; ++kx) {
                    float wv = wb[k * 5 + kx];
                    #pragma unroll
                    for (int o = 0; o < 4; ++o) {
                        #pragma unroll
                        for (int cc = 0; cc < 4; ++cc)
                            acc[o * 4 + cc] = fmaf(v[o + k][cc + kx], wv, acc[o * 4 + cc]);
                    }
                }
            }
        }
        float m = acc[0];
        #pragma unroll
        for (int i = 1; i < 16; ++i) m = fmaxf(m, acc[i]);
        s_h2[tid] = fmaxf(m + cb2[oc], 0.f);
    }
    __syncthreads();

    if (tid < 150) {
        const float* w = w3 + tid * 320;
        float a0 = b3[tid], a1 = 0.f, a2 = 0.f, a3 = 0.f;
        for (int k = 0; k < 320; k += 4) {
            a0 = fmaf(s_h2[k],     w[k],     a0);
            a1 = fmaf(s_h2[k + 1], w[k + 1], a1);
            a2 = fmaf(s_h2[k + 2], w[k + 2], a2);
            a3 = fmaf(s_h2[k + 3], w[k + 3], a3);
        }
        s_t1[tid] = fmaxf((a0 + a1) + (a2 + a3), 0.f);
    }
    __syncthreads();

    if (tid < 100) {
        const float* w = w4 + tid * 150;
        float a0 = b4[tid], a1 = 0.f;
        for (int k = 0; k < 150; k += 2) {
            a0 = fmaf(s_t1[k],     w[k],     a0);
            a1 = fmaf(s_t1[k + 1], w[k + 1], a1);
        }
        s_hc[tid] = fmaxf(a0 + a1, 0.f);
    }
    if (tid >= 100 && tid < 145) s_hc[tid] = xtraj[b * 45 + (tid - 100)];
    __syncthreads();

    if (tid < 100) {
        const float* w = pw1 + tid * 145;
        float acc = pb1[tid];
        for (int k = 0; k < 145; ++k) acc = fmaf(s_hc[k], w[k], acc);
        s_m1[tid] = fmaxf(acc, 0.f);
    } else if (tid >= 128 && tid < 228) {
        int i = tid - 128;
        const float* w = vw1 + i * 145;
        float acc = vb1[i];
        for (int k = 0; k < 145; ++k) acc = fmaf(s_hc[k], w[k], acc);
        s_m1[tid] = fmaxf(acc, 0.f);
    }
    __syncthreads();

    if (tid < 100) {
        const float* w = pw2 + tid * 100;
        float acc = pb2[tid];
        for (int k = 0; k < 100; ++k) acc = fmaf(s_m1[k], w[k], acc);
        s_m2[tid] = fmaxf(acc, 0.f);
    } else if (tid >= 128 && tid < 228) {
        int i = tid - 128;
        const float* w = vw2 + i * 100;
        float acc = vb2[i];
        for (int k = 0; k < 100; ++k) acc = fmaf(s_m1[128 + k], w[k], acc);
        s_m2[tid] = fmaxf(acc, 0.f);
    }
    __syncthreads();

    if (tid < 20) {
        const float* w = pw3 + tid * 100;
        float acc = pb3[tid];
        for (int k = 0; k < 100; ++k) acc = fmaf(s_m2[k], w[k], acc);
        ws_pr[b * 20 + tid] = acc;
        out[b * 100 + 40 + tid] = 1000.f * (acc - x[b * 160 + tid]);
    } else if (tid >= 128 && tid < 168) {
        int i = tid - 128;
        const float* w = vw3 + i * 100;
        float acc = vb3[i];
        for (int k = 0; k < 100; ++k) acc = fmaf(s_m2[128 + k], w[k], acc);
        ws_v[b * 40 + i] = acc;
        out[b * 100 + 60 + i] = 1000.f * (acc - x[b * 160 + 120 + i]);
    }
}

// ---------------------------------------------------------------------------
// K3: normal-equation PDHG. 32 lanes per problem (2 problems/wave).
// Maintain q = A^T y:  q += tau*(M*zb - A^T b),  z = prox(z - tau*q),
// with M = A^T A (<=10 nnz/row) -> ONE shuffle-gather per iteration instead
// of two dependent rounds. M coefficients computed numerically at setup from
// a dense A built in LDS via the (verified) AZ structure tables.
// ---------------------------------------------------------------------------
__device__ const signed char AZ_IDX[32][8] = {
    {4,5,6,7,8,9,0,0},{10,11,0,0,0,0,0,0},{4,5,6,7,8,9,10,11},
    {0,12,14,0,0,0,0,0},{2,12,14,0,0,0,0,0},{12,14,0,0,0,0,0,0},
    {1,13,15,0,0,0,0,0},{3,13,15,0,0,0,0,0},{13,15,0,0,0,0,0,0},
    {16,18,4,0,0,0,0,0},{16,18,6,0,0,0,0,0},{17,19,5,0,0,0,0,0},
    {17,19,7,0,0,0,0,0},{20,21,8,0,0,0,0,0},{20,21,10,0,0,0,0,0},
    {22,23,9,0,0,0,0,0},{22,23,11,0,0,0,0,0},
    {0},{0},{0},{0},{0},{0},{0},{0},{0},{0},{0},{0},{0},{0},{0}
};
__device__ const signed char AZ_SEL[32][8] = {
    {1,1,1,1,1,1,0,0},{1,1,0,0,0,0,0,0},{3,4,5,6,7,8,9,10},
    {1,11,13,0,0,0,0,0},{1,12,14,0,0,0,0,0},{1,1,0,0,0,0,0,0},
    {1,13,15,0,0,0,0,0},{1,14,16,0,0,0,0,0},{1,1,0,0,0,0,0,0},
    {17,19,2,0,0,0,0,0},{18,20,2,0,0,0,0,0},{19,21,2,0,0,0,0,0},
    {20,22,2,0,0,0,0,0},{23,25,2,0,0,0,0,0},{24,26,2,0,0,0,0,0},
    {27,29,2,0,0,0,0,0},{28,30,2,0,0,0,0,0},
    {0},{0},{0},{0},{0},{0},{0},{0},{0},{0},{0},{0},{0},{0},{0}
};
// Column supports of A (rows touching z-index l), 0-padded (A[0][l]==0 there).
__device__ const signed char AT_IDX[32][3] = {
    {3,0,0},{6,0,0},{4,0,0},{7,0,0},
    {0,2,9},{0,2,11},{0,2,10},{0,2,12},{0,2,13},{0,2,15},{1,2,14},{1,2,16},
    {3,4,5},{6,7,8},{3,4,5},{6,7,8},
    {9,10,0},{11,12,0},{9,10,0},{11,12,0},
    {13,14,0},{13,14,0},{15,16,0},{15,16,0},
    {0},{0},{0},{0},{0},{0},{0},{0}
};
// Sparsity of M = A^T A: nnz column lists per row (0-padded) + validity mask.
__device__ const signed char M_IDX[32][10] = {
    {0,12,14,0,0,0,0,0,0,0},
    {1,13,15,0,0,0,0,0,0,0},
    {2,12,14,0,0,0,0,0,0,0},
    {3,13,15,0,0,0,0,0,0,0},
    {4,5,6,7,8,9,10,11,16,18},
    {4,5,6,7,8,9,10,11,17,19},
    {4,5,6,7,8,9,10,11,16,18},
    {4,5,6,7,8,9,10,11,17,19},
    {4,5,6,7,8,9,10,11,20,21},
    {4,5,6,7,8,9,10,11,22,23},
    {4,5,6,7,8,9,10,11,20,21},
    {4,5,6,7,8,9,10,11,22,23},
    {0,2,12,14,0,0,0,0,0,0},
    {1,3,13,15,0,0,0,0,0,0},
    {0,2,12,14,0,0,0,0,0,0},
    {1,3,13,15,0,0,0,0,0,0},
    {4,6,16,18,0,0,0,0,0,0},
    {5,7,17,19,0,0,0,0,0,0},
    {4,6,16,18,0,0,0,0,0,0},
    {5,7,17,19,0,0,0,0,0,0},
    {8,10,20,21,0,0,0,0,0,0},
    {8,10,20,21,0,0,0,0,0,0},
    {9,11,22,23,0,0,0,0,0,0},
    {9,11,22,23,0,0,0,0,0,0},
    {0},{0},{0},{0},{0},{0},{0},{0}
};
__device__ const signed char M_MSK[32][10] = {
    {1,1,1,0,0,0,0,0,0,0},
    {1,1,1,0,0,0,0,0,0,0},
    {1,1,1,0,0,0,0,0,0,0},
    {1,1,1,0,0,0,0,0,0,0},
    {1,1,1,1,1,1,1,1,1,1},
    {1,1,1,1,1,1,1,1,1,1},
    {1,1,1,1,1,1,1,1,1,1},
    {1,1,1,1,1,1,1,1,1,1},
    {1,1,1,1,1,1,1,1,1,1},
    {1,1,1,1,1,1,1,1,1,1},
    {1,1,1,1,1,1,1,1,1,1},
    {1,1,1,1,1,1,1,1,1,1},
    {1,1,1,1,0,0,0,0,0,0},
    {1,1,1,1,0,0,0,0,0,0},
    {1,1,1,1,0,0,0,0,0,0},
    {1,1,1,1,0,0,0,0,0,0},
    {1,1,1,1,0,0,0,0,0,0},
    {1,1,1,1,0,0,0,0,0,0},
    {1,1,1,1,0,0,0,0,0,0},
    {1,1,1,1,0,0,0,0,0,0},
    {1,1,1,1,0,0,0,0,0,0},
    {1,1,1,1,0,0,0,0,0,0},
    {1,1,1,1,0,0,0,0,0,0},
    {1,1,1,1,0,0,0,0,0,0},
    {0},{0},{0},{0},{0},{0},{0},{0}
};

__global__ __launch_bounds__(64) void lp_kernel(
    const float* __restrict__ xtraj, const float* __restrict__ x,
    const float* __restrict__ ws_pr, const float* __restrict__ ws_v,
    float* __restrict__ out, int nprob)
{
    const int g = threadIdx.x >> 5;
    const int l = threadIdx.x & 31;
    const int p = blockIdx.x * 2 + g;
    const int pc = p < nprob ? p : nprob - 1;
    const int b = pc / 5, t = pc % 5;
    const float* xt = xtraj + b * 45;
    const float* xb = x + b * 160;

    __shared__ float s_val[2][32];
    __shared__ float s_A[2][17][24];
    __shared__ float s_b[2][17];

    // ---- value table (slots: 0:0 1:1 2:-1 3..10:c24..c211 11..16:-v0..-v5
    //      17..22:fc0..fc5 23..30:fe0..fe7) ----
    {
        float val = 0.f;
        if (l == 1) val = 1.f;
        else if (l == 2) val = -1.f;
        else if (l >= 3 && l <= 10) {
            float r0 = xt[t], r1 = xt[5 + t];
            switch (l) {
                case 3:  val = r1 - ws_pr[b * 20 + 10 + t]; break;
                case 4:  val = r1 - ws_pr[b * 20 + 15 + t]; break;
                case 5:  val = ws_pr[b * 20 + 0 + t] - r0;  break;
                case 6:  val = ws_pr[b * 20 + 5 + t] - r0;  break;
                case 7:  val = r1 - xb[60 + 10 + t]; break;
                case 8:  val = r1 - xb[60 + 15 + t]; break;
                case 9:  val = xb[60 + 0 + t] - r0;  break;
                default: val = xb[60 + 5 + t] - r0;  break;
            }
        }
        else if (l >= 11 && l <= 16) val = -ws_v[b * 40 + 5 * (l - 11) + t];
        else if (l >= 17 && l <= 22) val = xb[20 + 5 * (l - 17) + t];
        else if (l >= 23 && l <= 30) val = xb[80 + 5 * (l - 23) + t];
        s_val[g][l] = val;
    }
    // zero dense A
    for (int i = threadIdx.x; i < 2 * 17 * 24; i += 64) (&s_A[0][0][0])[i] = 0.f;
    __syncthreads();

    // ---- build dense A + b in LDS (lane e < 17 fills row e) ----
    if (l < 17) {
        #pragma unroll
        for (int k = 0; k < 8; ++k) {
            int sel = AZ_SEL[l][k];
            if (sel != 0) s_A[g][l][(int)AZ_IDX[l][k]] = s_val[g][sel];
        }
        float bb = 0.f;
        if (l == 0) bb = xt[30 + t];
        else if (l == 1) bb = xt[35 + t];
        else if (l == 2) bb = xt[40 + t];
        else if (l == 5 || l == 8) bb = 1.f;
        s_b[g][l] = bb;
    }
    __syncthreads();

    // ---- numeric M-row coefficients + c = (A^T b)_l ----
    float mcf[10];
    int midx[10];
    float cc = 0.f;
    #pragma unroll
    for (int k = 0; k < 10; ++k) { mcf[k] = 0.f; midx[k] = 0; }
    if (l < 24) {
        int e0 = AT_IDX[l][0], e1 = AT_IDX[l][1], e2 = AT_IDX[l][2];
        float a0 = s_A[g][e0][l], a1 = s_A[g][e1][l], a2 = s_A[g][e2][l];
        cc = a0 * s_b[g][e0] + a1 * s_b[g][e1] + a2 * s_b[g][e2];
        #pragma unroll
        for (int k = 0; k < 10; ++k) {
            int j = M_IDX[l][k];
            midx[k] = j;
            float m = a0 * s_A[g][e0][j] + a1 * s_A[g][e1][j] + a2 * s_A[g][e2][j];
            mcf[k] = (M_MSK[l][k] != 0) ? m : 0.f;
        }
    }

    const bool isF  = (l >= 4 && l < 8);
    const bool isNN = (l >= 12);

    // ---- spectral norm: 25 power iterations, u <- M u / ||M u|| ----
    float u = (l < 24) ? 1.f : 0.f;
    for (int it = 0; it < 25; ++it) {
        float w = 0.f;
        #pragma unroll
        for (int k = 0; k < 10; ++k) w = fmaf(mcf[k], __shfl(u, midx[k], 32), w);
        float s = w * w;
        s += __shfl_xor(s, 16, 32); s += __shfl_xor(s, 8, 32);
        s += __shfl_xor(s, 4, 32);  s += __shfl_xor(s, 2, 32);
        s += __shfl_xor(s, 1, 32);
        u = w / (sqrtf(s) + 1e-12f);
    }
    float tau;
    {
        float w = 0.f;
        #pragma unroll
        for (int k = 0; k < 10; ++k) w = fmaf(mcf[k], __shfl(u, midx[k], 32), w);
        float s2 = u * w;   // u^T M u = ||A u||^2
        s2 += __shfl_xor(s2, 16, 32); s2 += __shfl_xor(s2, 8, 32);
        s2 += __shfl_xor(s2, 4, 32);  s2 += __shfl_xor(s2, 2, 32);
        s2 += __shfl_xor(s2, 1, 32);
        tau = 0.9f / (sqrtf(fmaxf(s2, 0.f)) + 1e-8f);
    }

    // ---- PDHG, q-form: 400 iterations, one gather each ----
    float zv = 0.f, zbv = 0.f, qv = 0.f;
    for (int it = 0; it < 400; ++it) {
        float s = 0.f;
        #pragma unroll
        for (int k = 0; k < 10; ++k) s = fmaf(mcf[k], __shfl(zbv, midx[k], 32), s);
        qv = fmaf(tau, s - cc, qv);

        float gg = fmaf(-tau, qv, zv);
        float st = copysignf(fmaxf(fabsf(gg) - tau, 0.f), gg);
        float nn = fmaxf(gg, 0.f);
        float zn = isF ? st : (isNN ? nn : gg);
        zbv = 2.f * zn - zv;
        zv = zn;
    }

    if (p < nprob) {
        float* ob = out + b * 100;
        if (l < 4)      ob[l * 5 + t]            = 100.f * zv;
        else if (l < 8) ob[20 + (l - 4) * 5 + t] = 100.f * zv;
    }
}

extern "C" void kernel_launch(void* const* d_in, const int* in_sizes, int n_in,
                              void* d_out, int out_size, void* d_ws, size_t ws_size,
                              hipStream_t stream) {
    const float* xtraj = (const float*)d_in[0];
    const float* x     = (const float*)d_in[1];
    const float* x_img = (const float*)d_in[2];
    const float* cw1 = (const float*)d_in[3];
    const float* cb1 = (const float*)d_in[4];
    const float* cw2 = (const float*)d_in[5];
    const float* cb2 = (const float*)d_in[6];
    const float* w3  = (const float*)d_in[7];
    const float* b3  = (const float*)d_in[8];
    const float* w4  = (const float*)d_in[9];
    const float* b4  = (const float*)d_in[10];
    const float* pw1 = (const float*)d_in[11];
    const float* pb1 = (const float*)d_in[12];
    const float* pw2 = (const float*)d_in[13];
    const float* pb2 = (const float*)d_in[14];
    const float* pw3 = (const float*)d_in[15];
    const float* pb3 = (const float*)d_in[16];
    const float* vw1 = (const float*)d_in[17];
    const float* vb1 = (const float*)d_in[18];
    const float* vw2 = (const float*)d_in[19];
    const float* vb2 = (const float*)d_in[20];
    const float* vw3 = (const float*)d_in[21];
    const float* vb3 = (const float*)d_in[22];

    float* out = (float*)d_out;
    const int Bn = in_sizes[0] / 45;

    float* ws_pr = (float*)d_ws;              // Bn*20 floats
    float* ws_v  = ws_pr + (size_t)Bn * 20;   // Bn*40 floats
    float* ws_h1 = ws_v + (size_t)Bn * 40;    // Bn*4000 floats (~8.2 MB)

    conv1_kernel<<<Bn * 4, 128, 0, stream>>>(x_img, cw1, cb1, ws_h1);

    head_kernel<<<Bn, 320, 0, stream>>>(
        xtraj, x, ws_h1, cw2, cb2, w3, b3, w4, b4,
        pw1, pb1, pw2, pb2, pw3, pb3, vw1, vb1, vw2, vb2, vw3, vb3,
        out, ws_pr, ws_v);

    const int nprob = Bn * 5;
    lp_kernel<<<(nprob + 1) / 2, 64, 0, stream>>>(xtraj, x, ws_pr, ws_v, out, nprob);
}